// Round 6
// baseline (105.822 us; speedup 1.0000x reference)
//
#include <hip/hip_runtime.h>

// Problem constants
#define BB 4
#define RR 384
#define CC 384
#define EE 512
#define HH 16
#define DD 32
#define MROWS 1536   // B*R = B*C

typedef __attribute__((ext_vector_type(8))) short bf16x8;   // 8 bf16 = 4 VGPRs
typedef __attribute__((ext_vector_type(4))) float f32x4;

// ---------------------------------------------------------------------------
// f32 -> (hi, lo) bf16 split, RNE both times. x ~= hi + lo with ~2^-16 rel err.
// ---------------------------------------------------------------------------
__device__ __forceinline__ void split1(float x, ushort& h, ushort& l)
{
    const unsigned u = __float_as_uint(x);
    const unsigned r = (u + 0x7fffu + ((u >> 16) & 1u)) >> 16;
    h = (ushort)r;
    const float hf = __uint_as_float(r << 16);
    const float lo = x - hf;
    const unsigned u2 = __float_as_uint(lo);
    l = (ushort)((u2 + 0x7fffu + ((u2 >> 16) & 1u)) >> 16);
}

// Packed fragment address for element (r, k) of a [rows][512] matrix:
// lane l of the wave covering (r-tile, k-tile) reads elems [l*8, l*8+8).
__device__ __forceinline__ int packed_addr(int r, int k)
{
    return ((r >> 4) * 16 + (k >> 5)) * 512 + ((k >> 3) & 3) * 128 + (r & 15) * 8 + (k & 7);
}

// ---------------------------------------------------------------------------
// Split kernel: 6 arrays -> hi/lo bf16 planes in PACKED fragment layout.
// ---------------------------------------------------------------------------
__global__ __launch_bounds__(256) void split_kernel(
    const float* __restrict__ rowe, const float* __restrict__ cole,
    const float* __restrict__ Wq, const float* __restrict__ Wk,
    const float* __restrict__ Wv, const float* __restrict__ Wo,
    ushort* __restrict__ reh, ushort* __restrict__ rel,
    ushort* __restrict__ ceh, ushort* __restrict__ cel,
    ushort* __restrict__ wqh, ushort* __restrict__ wql,
    ushort* __restrict__ wkh, ushort* __restrict__ wkl,
    ushort* __restrict__ wvh, ushort* __restrict__ wvl,
    ushort* __restrict__ woh, ushort* __restrict__ wol)
{
    const float* src; ushort* dh; ushort* dl; int n;
    switch (blockIdx.y) {
    case 0: src = rowe; dh = reh; dl = rel; n = MROWS * EE; break;
    case 1: src = cole; dh = ceh; dl = cel; n = MROWS * EE; break;
    case 2: src = Wq;   dh = wqh; dl = wql; n = EE * EE;    break;
    case 3: src = Wk;   dh = wkh; dl = wkl; n = EE * EE;    break;
    case 4: src = Wv;   dh = wvh; dl = wvl; n = EE * EE;    break;
    default: src = Wo;  dh = woh; dl = wol; n = EE * EE;    break;
    }
    const int i4 = blockIdx.x * 256 + threadIdx.x;
    if (i4 * 4 >= n) return;
    const float4 v = ((const float4*)src)[i4];
    ushort4 hs, ls;
    split1(v.x, hs.x, ls.x);
    split1(v.y, hs.y, ls.y);
    split1(v.z, hs.z, ls.z);
    split1(v.w, hs.w, ls.w);
    const int e0 = i4 * 4;
    const int dst = packed_addr(e0 >> 9, e0 & 511);   // (k&7) in {0,4}: aligned
    *(ushort4*)(dh + dst) = hs;
    *(ushort4*)(dl + dst) = ls;
}

// ---------------------------------------------------------------------------
// bf16x3 emulated-f32 GEMM on packed operands.
// Wave owns m-tile Mt (16 rows) x 4 n-tiles (64 cols). Every operand load is
// one contiguous 1KB wave transaction; depth-1 register pipeline on K.
// ---------------------------------------------------------------------------
__device__ __forceinline__ void gemm_bf16x3_body(
    const ushort* __restrict__ Ahi, const ushort* __restrict__ Alo,
    const ushort* __restrict__ Whi, const ushort* __restrict__ Wlo,
    const float* __restrict__ bias, float* __restrict__ Y,
    int Mt, int Nt0)
{
    constexpr int N = 512;
    const int lane = threadIdx.x & 63;
    const int col = lane & 15, kgrp = lane >> 4;

    const ushort* pah = Ahi + (size_t)Mt * 8192 + lane * 8;
    const ushort* pal = Alo + (size_t)Mt * 8192 + lane * 8;
    const ushort* pbh = Whi + (size_t)Nt0 * 8192 + lane * 8;
    const ushort* pbl = Wlo + (size_t)Nt0 * 8192 + lane * 8;

    f32x4 acc0 = {}, acc1 = {}, acc2 = {}, acc3 = {};

    bf16x8 ah  = *(const bf16x8*)(pah);
    bf16x8 al  = *(const bf16x8*)(pal);
    bf16x8 bh0 = *(const bf16x8*)(pbh);
    bf16x8 bh1 = *(const bf16x8*)(pbh + 8192);
    bf16x8 bh2 = *(const bf16x8*)(pbh + 16384);
    bf16x8 bh3 = *(const bf16x8*)(pbh + 24576);
    bf16x8 bl0 = *(const bf16x8*)(pbl);
    bf16x8 bl1 = *(const bf16x8*)(pbl + 8192);
    bf16x8 bl2 = *(const bf16x8*)(pbl + 16384);
    bf16x8 bl3 = *(const bf16x8*)(pbl + 24576);

#pragma unroll 4
    for (int kt = 0; kt < 16; ++kt) {
        bf16x8 nah = ah, nal = al;
        bf16x8 nbh0 = bh0, nbh1 = bh1, nbh2 = bh2, nbh3 = bh3;
        bf16x8 nbl0 = bl0, nbl1 = bl1, nbl2 = bl2, nbl3 = bl3;
        if (kt < 15) {
            const int ko = (kt + 1) * 512;
            nah  = *(const bf16x8*)(pah + ko);
            nal  = *(const bf16x8*)(pal + ko);
            nbh0 = *(const bf16x8*)(pbh + ko);
            nbh1 = *(const bf16x8*)(pbh + ko + 8192);
            nbh2 = *(const bf16x8*)(pbh + ko + 16384);
            nbh3 = *(const bf16x8*)(pbh + ko + 24576);
            nbl0 = *(const bf16x8*)(pbl + ko);
            nbl1 = *(const bf16x8*)(pbl + ko + 8192);
            nbl2 = *(const bf16x8*)(pbl + ko + 16384);
            nbl3 = *(const bf16x8*)(pbl + ko + 24576);
        }
        acc0 = __builtin_amdgcn_mfma_f32_16x16x32_bf16(ah, bh0, acc0, 0, 0, 0);
        acc0 = __builtin_amdgcn_mfma_f32_16x16x32_bf16(ah, bl0, acc0, 0, 0, 0);
        acc0 = __builtin_amdgcn_mfma_f32_16x16x32_bf16(al, bh0, acc0, 0, 0, 0);
        acc1 = __builtin_amdgcn_mfma_f32_16x16x32_bf16(ah, bh1, acc1, 0, 0, 0);
        acc1 = __builtin_amdgcn_mfma_f32_16x16x32_bf16(ah, bl1, acc1, 0, 0, 0);
        acc1 = __builtin_amdgcn_mfma_f32_16x16x32_bf16(al, bh1, acc1, 0, 0, 0);
        acc2 = __builtin_amdgcn_mfma_f32_16x16x32_bf16(ah, bh2, acc2, 0, 0, 0);
        acc2 = __builtin_amdgcn_mfma_f32_16x16x32_bf16(ah, bl2, acc2, 0, 0, 0);
        acc2 = __builtin_amdgcn_mfma_f32_16x16x32_bf16(al, bh2, acc2, 0, 0, 0);
        acc3 = __builtin_amdgcn_mfma_f32_16x16x32_bf16(ah, bh3, acc3, 0, 0, 0);
        acc3 = __builtin_amdgcn_mfma_f32_16x16x32_bf16(ah, bl3, acc3, 0, 0, 0);
        acc3 = __builtin_amdgcn_mfma_f32_16x16x32_bf16(al, bh3, acc3, 0, 0, 0);
        ah = nah; al = nal;
        bh0 = nbh0; bh1 = nbh1; bh2 = nbh2; bh3 = nbh3;
        bl0 = nbl0; bl1 = nbl1; bl2 = nbl2; bl3 = nbl3;
    }

    const f32x4 accs[4] = {acc0, acc1, acc2, acc3};
#pragma unroll
    for (int t = 0; t < 4; ++t) {
        const int n = (Nt0 + t) * 16 + col;
        const float bn = bias[n];
#pragma unroll
        for (int j = 0; j < 4; ++j) {
            const int m = Mt * 16 + kgrp * 4 + j;
            Y[m * N + n] = accs[t][j] + bn;
        }
    }
}

// XCD-grouping swizzle: l = a + 8b + 64c (a,b in [0,8), c in [0,3))
//  -> Bm = 3a + c (m-strip), Bx = b. Same-Bm blocks share l%8 -> same XCD.
__global__ __launch_bounds__(256) void qkv_kernel(
    const ushort* __restrict__ reh, const ushort* __restrict__ rel,
    const ushort* __restrict__ ceh, const ushort* __restrict__ cel,
    const ushort* __restrict__ wqh, const ushort* __restrict__ wql,
    const ushort* __restrict__ wkh, const ushort* __restrict__ wkl,
    const ushort* __restrict__ wvh, const ushort* __restrict__ wvl,
    const float* __restrict__ bq, const float* __restrict__ bk,
    const float* __restrict__ bv,
    float* __restrict__ Qo, float* __restrict__ Ko, float* __restrict__ Vo)
{
    const int l = blockIdx.x + (blockIdx.y << 3);
    const int Bm = (l & 7) * 3 + (l >> 6);
    const int Bx = (l >> 3) & 7;
    const int Mt = Bm * 4 + (threadIdx.x >> 6);
    const int Nt0 = Bx * 4;
    if (blockIdx.z == 0)      gemm_bf16x3_body(reh, rel, wqh, wql, bq, Qo, Mt, Nt0);
    else if (blockIdx.z == 1) gemm_bf16x3_body(ceh, cel, wkh, wkl, bk, Ko, Mt, Nt0);
    else                      gemm_bf16x3_body(ceh, cel, wvh, wvl, bv, Vo, Mt, Nt0);
}

__global__ __launch_bounds__(256) void oproj_kernel(
    const ushort* __restrict__ hbh, const ushort* __restrict__ hbl,
    const ushort* __restrict__ woh, const ushort* __restrict__ wol,
    const float* __restrict__ bo, float* __restrict__ out)
{
    const int l = blockIdx.x + (blockIdx.y << 3);
    const int Bm = (l & 7) * 3 + (l >> 6);
    const int Bx = (l >> 3) & 7;
    const int Mt = Bm * 4 + (threadIdx.x >> 6);
    const int Nt0 = Bx * 4;
    gemm_bf16x3_body(hbh, hbl, woh, wol, bo, out, Mt, Nt0);
}

// ---------------------------------------------------------------------------
// Vsum kernel: Vsum[b][h][d] = sum_c V[b][c][h*32+d]. Grid (16,4), 256 thr.
// ---------------------------------------------------------------------------
__global__ __launch_bounds__(256) void vsum_kernel(const float* __restrict__ Vb,
                                                   float* __restrict__ Vsum)
{
    __shared__ float part[8][32];
    const int h = blockIdx.x, b = blockIdx.y;
    const int d = threadIdx.x & 31, g = threadIdx.x >> 5;
    float acc = 0.f;
    for (int c = g; c < CC; c += 8)
        acc += Vb[(b * CC + c) * EE + h * DD + d];
    part[g][d] = acc;
    __syncthreads();
    if (g == 0) {
        float s = 0.f;
#pragma unroll
        for (int gg = 0; gg < 8; ++gg) s += part[gg][d];
        Vsum[(b * HH + h) * DD + d] = s;
    }
}

// ---------------------------------------------------------------------------
// Semi-sparse attention, wave-per-(row, head-half), XCD-pinned by (b,hh).
// Fixed-max softmax: scores = tanh*10 in (-10,10), beta = background score,
// so m=10 is a valid global max. p = exp(s-10), no online rescale; all edge
// chunks are independent. Background handled analytically:
//   out = (sum_E (p_e - e^{b-10}) V_e + e^{b-10} Vsum) / (sum p + (C-nE) e^{b-10})
// V rows for a chunk are batch-loaded into registers before scoring so their
// latency hides under the dot+MLP computation.
// ---------------------------------------------------------------------------
__global__ __launch_bounds__(64, 3) void attn_kernel(
    const float* __restrict__ Qb, const float* __restrict__ Kb, const float* __restrict__ Vb,
    const float* __restrict__ cost,
    const float* __restrict__ W1, const float* __restrict__ b1,
    const float* __restrict__ W2, const float* __restrict__ b2,
    const float* __restrict__ beta,
    const float* __restrict__ Vsum,
    ushort* __restrict__ Hbh, ushort* __restrict__ Hbl)
{
    __shared__ int   ec[CC];
    __shared__ float ecw[CC];

    const int combo = blockIdx.x;      // 0..7 -> XCD (grid.x=8 => linear%8)
    const int b = combo >> 1;
    const int hh = combo & 1;
    const int r = blockIdx.y;          // 0..383
    const int lane = threadIdx.x;      // 0..63
    const int h = (lane & 7) + hh * 8;
    const int g = lane >> 3;           // 0..7 : eoff (scoring) / dgroup (PV)

    // ---- edge compaction (once per row-wave, shared by 8 heads) ----
    const float* crow = cost + (b * RR + r) * CC;
    int nE = 0;
    const unsigned long long prefix = (1ull << lane) - 1ull;
#pragma unroll
    for (int j = 0; j < 6; ++j) {
        const float cw = crow[lane + 64 * j];
        const unsigned long long mk = __ballot(cw > 0.f);
        if (cw > 0.f) {
            const int slot = nE + __popcll(mk & prefix);
            ec[slot]  = lane + 64 * j;
            ecw[slot] = cw;
        }
        nE += __popcll(mk);
    }
    __syncthreads();

    // ---- per-lane head state ----
    float qr[32];
    {
        const float4* qp = (const float4*)(Qb + (b * RR + r) * EE + h * DD);
#pragma unroll
        for (int dq = 0; dq < 8; ++dq) {
            const float4 v = qp[dq];
            qr[dq * 4 + 0] = v.x; qr[dq * 4 + 1] = v.y;
            qr[dq * 4 + 2] = v.z; qr[dq * 4 + 3] = v.w;
        }
    }
    float w10[16], w11[16], b1h[16], w2h[16];
    {
        const float4* p0 = (const float4*)(W1 + h * 32);
        const float4* p1 = (const float4*)(W1 + h * 32 + 16);
        const float4* pb = (const float4*)(b1 + h * 16);
        const float4* p2 = (const float4*)(W2 + h * 16);
#pragma unroll
        for (int q4 = 0; q4 < 4; ++q4) {
            const float4 a0 = p0[q4], a1 = p1[q4], ab = pb[q4], a2 = p2[q4];
            w10[q4*4+0]=a0.x; w10[q4*4+1]=a0.y; w10[q4*4+2]=a0.z; w10[q4*4+3]=a0.w;
            w11[q4*4+0]=a1.x; w11[q4*4+1]=a1.y; w11[q4*4+2]=a1.z; w11[q4*4+3]=a1.w;
            b1h[q4*4+0]=ab.x; b1h[q4*4+1]=ab.y; b1h[q4*4+2]=ab.z; b1h[q4*4+3]=ab.w;
            w2h[q4*4+0]=a2.x; w2h[q4*4+1]=a2.y; w2h[q4*4+2]=a2.z; w2h[q4*4+3]=a2.w;
        }
    }
    const float b2h = b2[h];
    const float betah = beta[h];
    const float scale = 0.17677669529663687f;  // 1/sqrt(32)
    const float ebeta = __expf(betah - 10.f);

    float Zl = 0.f;
    float apv[4] = {0.f, 0.f, 0.f, 0.f};

    for (int e0 = 0; e0 < nE; e0 += 8) {
        const int lim = (nE - e0 < 8) ? (nE - e0) : 8;

        // ---- batch V-row loads first: latency hides under scoring ----
        float4 vv[8];
#pragma unroll
        for (int eo = 0; eo < 8; ++eo) {
            int idx = e0 + eo; idx = (idx < nE) ? idx : (nE - 1);
            vv[eo] = *(const float4*)(Vb + (b * CC + ec[idx]) * EE + h * DD + g * 4);
        }

        // ---- score my edge (h = lane&7, e = e0 + g) ----
        const int e = e0 + g;
        float p = 0.f;
        if (e < nE) {
            const int c = ec[e];
            const float cw = ecw[e];
            const float* kp = Kb + (b * CC + c) * EE + h * DD;
            float d0 = 0.f, d1 = 0.f, d2 = 0.f, d3 = 0.f;
#pragma unroll
            for (int dq = 0; dq < 8; ++dq) {
                const float4 kv = *(const float4*)(kp + dq * 4);
                d0 = fmaf(qr[dq * 4 + 0], kv.x, d0);
                d1 = fmaf(qr[dq * 4 + 1], kv.y, d1);
                d2 = fmaf(qr[dq * 4 + 2], kv.z, d2);
                d3 = fmaf(qr[dq * 4 + 3], kv.w, d3);
            }
            const float dot = ((d0 + d1) + (d2 + d3)) * scale;
            float l0 = b2h, l1 = 0.f;
#pragma unroll
            for (int mm = 0; mm < 16; mm += 2) {
                const float h0 = fmaf(dot, w10[mm],     fmaf(cw, w11[mm],     b1h[mm]));
                const float h1 = fmaf(dot, w10[mm + 1], fmaf(cw, w11[mm + 1], b1h[mm + 1]));
                l0 = fmaf(fmaxf(h0, 0.f), w2h[mm],     l0);
                l1 = fmaf(fmaxf(h1, 0.f), w2h[mm + 1], l1);
            }
            const float logit = l0 + l1;
            // s = tanh(logit)*10; p = exp(s - 10) = exp(-20/(e^{2x}+1))
            const float ex = __expf(2.f * logit);
            p = __expf(-20.f / (ex + 1.f));
        }
        Zl += p;

        // ---- PV: redistribute p via shfl, weight = p - ebeta ----
#pragma unroll
        for (int eo = 0; eo < 8; ++eo) {
            const float pb = __shfl(p, (lane & 7) + 8 * eo);
            const float w = (eo < lim) ? (pb - ebeta) : 0.f;
            apv[0] = fmaf(w, vv[eo].x, apv[0]);
            apv[1] = fmaf(w, vv[eo].y, apv[1]);
            apv[2] = fmaf(w, vv[eo].z, apv[2]);
            apv[3] = fmaf(w, vv[eo].w, apv[3]);
        }
    }

    // ---- Z reduce over the 8 lanes sharing h ----
    float Zr = Zl;
    Zr += __shfl_xor(Zr, 8);
    Zr += __shfl_xor(Zr, 16);
    Zr += __shfl_xor(Zr, 32);
    const float Z = Zr + (float)(CC - nE) * ebeta;
    const float inv = 1.f / Z;

    const float4 vs = *(const float4*)(Vsum + (b * HH + h) * DD + g * 4);
    float4 o;
    o.x = (apv[0] + ebeta * vs.x) * inv;
    o.y = (apv[1] + ebeta * vs.y) * inv;
    o.z = (apv[2] + ebeta * vs.z) * inv;
    o.w = (apv[3] + ebeta * vs.w) * inv;

    ushort4 oh, ol;
    split1(o.x, oh.x, ol.x);
    split1(o.y, oh.y, ol.y);
    split1(o.z, oh.z, ol.z);
    split1(o.w, oh.w, ol.w);
    // packed write: r_m = b*RR+r, k = h*32 + g*4
    const int rm = b * RR + r;
    const int dstp = ((rm >> 4) * 16 + h) * 512 + (g >> 1) * 128 + (rm & 15) * 8 + (g & 1) * 4;
    *(ushort4*)(Hbh + dstp) = oh;
    *(ushort4*)(Hbl + dstp) = ol;
}

// ---------------------------------------------------------------------------
extern "C" void kernel_launch(void* const* d_in, const int* in_sizes, int n_in,
                              void* d_out, int out_size, void* d_ws, size_t ws_size,
                              hipStream_t stream)
{
    const float* rowe = (const float*)d_in[0];
    const float* cole = (const float*)d_in[1];
    const float* cost = (const float*)d_in[2];
    const float* Wq   = (const float*)d_in[3];
    const float* bq   = (const float*)d_in[4];
    const float* Wk   = (const float*)d_in[5];
    const float* bk   = (const float*)d_in[6];
    const float* Wv   = (const float*)d_in[7];
    const float* bv   = (const float*)d_in[8];
    const float* Wo   = (const float*)d_in[9];
    const float* bo   = (const float*)d_in[10];
    const float* W1   = (const float*)d_in[11];
    const float* b1   = (const float*)d_in[12];
    const float* W2   = (const float*)d_in[13];
    const float* b2   = (const float*)d_in[14];
    const float* beta = (const float*)d_in[15];
    float* out = (float*)d_out;

    // ---- workspace carve ----
    char* cur = (char*)d_ws;
    float* Qb   = (float*)cur; cur += (size_t)MROWS * EE * 4;
    float* Kb   = (float*)cur; cur += (size_t)MROWS * EE * 4;
    float* Vb   = (float*)cur; cur += (size_t)MROWS * EE * 4;
    float* Vsum = (float*)cur; cur += (size_t)BB * HH * DD * 4;
    ushort* reh = (ushort*)cur; cur += (size_t)MROWS * EE * 2;
    ushort* rel = (ushort*)cur; cur += (size_t)MROWS * EE * 2;
    ushort* ceh = (ushort*)cur; cur += (size_t)MROWS * EE * 2;
    ushort* cel = (ushort*)cur; cur += (size_t)MROWS * EE * 2;
    ushort* wqh = (ushort*)cur; cur += (size_t)EE * EE * 2;
    ushort* wql = (ushort*)cur; cur += (size_t)EE * EE * 2;
    ushort* wkh = (ushort*)cur; cur += (size_t)EE * EE * 2;
    ushort* wkl = (ushort*)cur; cur += (size_t)EE * EE * 2;
    ushort* wvh = (ushort*)cur; cur += (size_t)EE * EE * 2;
    ushort* wvl = (ushort*)cur; cur += (size_t)EE * EE * 2;
    ushort* woh = (ushort*)cur; cur += (size_t)EE * EE * 2;
    ushort* wol = (ushort*)cur; cur += (size_t)EE * EE * 2;
    ushort* hbh = (ushort*)cur; cur += (size_t)MROWS * EE * 2;
    ushort* hbl = (ushort*)cur; cur += (size_t)MROWS * EE * 2;

    split_kernel<<<dim3(768, 6), 256, 0, stream>>>(
        rowe, cole, Wq, Wk, Wv, Wo,
        reh, rel, ceh, cel, wqh, wql, wkh, wkl, wvh, wvl, woh, wol);

    dim3 g1(8, 24, 3);
    qkv_kernel<<<g1, 256, 0, stream>>>(reh, rel, ceh, cel,
                                       wqh, wql, wkh, wkl, wvh, wvl,
                                       bq, bk, bv, Qb, Kb, Vb);

    dim3 gv(16, 4);
    vsum_kernel<<<gv, 256, 0, stream>>>(Vb, Vsum);

    dim3 g2(8, RR);   // x = (b,hh) combo -> XCD pin; y = row
    attn_kernel<<<g2, 64, 0, stream>>>(Qb, Kb, Vb, cost, W1, b1, W2, b2, beta,
                                       Vsum, hbh, hbl);

    dim3 g3(8, 24, 1);
    oproj_kernel<<<g3, 256, 0, stream>>>(hbh, hbl, woh, wol, bo, out);
}

// Round 7
// 97.851 us; speedup vs baseline: 1.0815x; 1.0815x over previous
//
#include <hip/hip_runtime.h>

// Problem constants
#define BB 4
#define RR 384
#define CC 384
#define EE 512
#define HH 16
#define DD 32
#define MROWS 1536   // B*R = B*C
#define MAXE 128     // edge-list stride (nE ~ 38 +- 6; 128 = 15 sigma)

typedef __attribute__((ext_vector_type(8))) short bf16x8;   // 8 bf16 = 4 VGPRs
typedef __attribute__((ext_vector_type(4))) float f32x4;

// ---------------------------------------------------------------------------
// f32 -> (hi, lo) bf16 split, RNE both times. x ~= hi + lo with ~2^-16 rel err.
// ---------------------------------------------------------------------------
__device__ __forceinline__ void split1(float x, ushort& h, ushort& l)
{
    const unsigned u = __float_as_uint(x);
    const unsigned r = (u + 0x7fffu + ((u >> 16) & 1u)) >> 16;
    h = (ushort)r;
    const float hf = __uint_as_float(r << 16);
    const float lo = x - hf;
    const unsigned u2 = __float_as_uint(lo);
    l = (ushort)((u2 + 0x7fffu + ((u2 >> 16) & 1u)) >> 16);
}

// Packed fragment address for element (r, k) of a [rows][512] matrix:
// lane l of the wave covering (r-tile, k-tile) reads elems [l*8, l*8+8).
__device__ __forceinline__ int packed_addr(int r, int k)
{
    return ((r >> 4) * 16 + (k >> 5)) * 512 + ((k >> 3) & 3) * 128 + (r & 15) * 8 + (k & 7);
}

// ---------------------------------------------------------------------------
// Split kernel: 6 arrays -> hi/lo bf16 planes in PACKED fragment layout.
// ---------------------------------------------------------------------------
__global__ __launch_bounds__(256) void split_kernel(
    const float* __restrict__ rowe, const float* __restrict__ cole,
    const float* __restrict__ Wq, const float* __restrict__ Wk,
    const float* __restrict__ Wv, const float* __restrict__ Wo,
    ushort* __restrict__ reh, ushort* __restrict__ rel,
    ushort* __restrict__ ceh, ushort* __restrict__ cel,
    ushort* __restrict__ wqh, ushort* __restrict__ wql,
    ushort* __restrict__ wkh, ushort* __restrict__ wkl,
    ushort* __restrict__ wvh, ushort* __restrict__ wvl,
    ushort* __restrict__ woh, ushort* __restrict__ wol)
{
    const float* src; ushort* dh; ushort* dl; int n;
    switch (blockIdx.y) {
    case 0: src = rowe; dh = reh; dl = rel; n = MROWS * EE; break;
    case 1: src = cole; dh = ceh; dl = cel; n = MROWS * EE; break;
    case 2: src = Wq;   dh = wqh; dl = wql; n = EE * EE;    break;
    case 3: src = Wk;   dh = wkh; dl = wkl; n = EE * EE;    break;
    case 4: src = Wv;   dh = wvh; dl = wvl; n = EE * EE;    break;
    default: src = Wo;  dh = woh; dl = wol; n = EE * EE;    break;
    }
    const int i4 = blockIdx.x * 256 + threadIdx.x;
    if (i4 * 4 >= n) return;
    const float4 v = ((const float4*)src)[i4];
    ushort4 hs, ls;
    split1(v.x, hs.x, ls.x);
    split1(v.y, hs.y, ls.y);
    split1(v.z, hs.z, ls.z);
    split1(v.w, hs.w, ls.w);
    const int e0 = i4 * 4;
    const int dst = packed_addr(e0 >> 9, e0 & 511);   // (k&7) in {0,4}: aligned
    *(ushort4*)(dh + dst) = hs;
    *(ushort4*)(dl + dst) = ls;
}

// ---------------------------------------------------------------------------
// bf16x3 emulated-f32 GEMM on packed operands.
// ---------------------------------------------------------------------------
__device__ __forceinline__ void gemm_bf16x3_body(
    const ushort* __restrict__ Ahi, const ushort* __restrict__ Alo,
    const ushort* __restrict__ Whi, const ushort* __restrict__ Wlo,
    const float* __restrict__ bias, float* __restrict__ Y,
    int Mt, int Nt0)
{
    constexpr int N = 512;
    const int lane = threadIdx.x & 63;
    const int col = lane & 15, kgrp = lane >> 4;

    const ushort* pah = Ahi + (size_t)Mt * 8192 + lane * 8;
    const ushort* pal = Alo + (size_t)Mt * 8192 + lane * 8;
    const ushort* pbh = Whi + (size_t)Nt0 * 8192 + lane * 8;
    const ushort* pbl = Wlo + (size_t)Nt0 * 8192 + lane * 8;

    f32x4 acc0 = {}, acc1 = {}, acc2 = {}, acc3 = {};

    bf16x8 ah  = *(const bf16x8*)(pah);
    bf16x8 al  = *(const bf16x8*)(pal);
    bf16x8 bh0 = *(const bf16x8*)(pbh);
    bf16x8 bh1 = *(const bf16x8*)(pbh + 8192);
    bf16x8 bh2 = *(const bf16x8*)(pbh + 16384);
    bf16x8 bh3 = *(const bf16x8*)(pbh + 24576);
    bf16x8 bl0 = *(const bf16x8*)(pbl);
    bf16x8 bl1 = *(const bf16x8*)(pbl + 8192);
    bf16x8 bl2 = *(const bf16x8*)(pbl + 16384);
    bf16x8 bl3 = *(const bf16x8*)(pbl + 24576);

#pragma unroll 4
    for (int kt = 0; kt < 16; ++kt) {
        bf16x8 nah = ah, nal = al;
        bf16x8 nbh0 = bh0, nbh1 = bh1, nbh2 = bh2, nbh3 = bh3;
        bf16x8 nbl0 = bl0, nbl1 = bl1, nbl2 = bl2, nbl3 = bl3;
        if (kt < 15) {
            const int ko = (kt + 1) * 512;
            nah  = *(const bf16x8*)(pah + ko);
            nal  = *(const bf16x8*)(pal + ko);
            nbh0 = *(const bf16x8*)(pbh + ko);
            nbh1 = *(const bf16x8*)(pbh + ko + 8192);
            nbh2 = *(const bf16x8*)(pbh + ko + 16384);
            nbh3 = *(const bf16x8*)(pbh + ko + 24576);
            nbl0 = *(const bf16x8*)(pbl + ko);
            nbl1 = *(const bf16x8*)(pbl + ko + 8192);
            nbl2 = *(const bf16x8*)(pbl + ko + 16384);
            nbl3 = *(const bf16x8*)(pbl + ko + 24576);
        }
        acc0 = __builtin_amdgcn_mfma_f32_16x16x32_bf16(ah, bh0, acc0, 0, 0, 0);
        acc0 = __builtin_amdgcn_mfma_f32_16x16x32_bf16(ah, bl0, acc0, 0, 0, 0);
        acc0 = __builtin_amdgcn_mfma_f32_16x16x32_bf16(al, bh0, acc0, 0, 0, 0);
        acc1 = __builtin_amdgcn_mfma_f32_16x16x32_bf16(ah, bh1, acc1, 0, 0, 0);
        acc1 = __builtin_amdgcn_mfma_f32_16x16x32_bf16(ah, bl1, acc1, 0, 0, 0);
        acc1 = __builtin_amdgcn_mfma_f32_16x16x32_bf16(al, bh1, acc1, 0, 0, 0);
        acc2 = __builtin_amdgcn_mfma_f32_16x16x32_bf16(ah, bh2, acc2, 0, 0, 0);
        acc2 = __builtin_amdgcn_mfma_f32_16x16x32_bf16(ah, bl2, acc2, 0, 0, 0);
        acc2 = __builtin_amdgcn_mfma_f32_16x16x32_bf16(al, bh2, acc2, 0, 0, 0);
        acc3 = __builtin_amdgcn_mfma_f32_16x16x32_bf16(ah, bh3, acc3, 0, 0, 0);
        acc3 = __builtin_amdgcn_mfma_f32_16x16x32_bf16(ah, bl3, acc3, 0, 0, 0);
        acc3 = __builtin_amdgcn_mfma_f32_16x16x32_bf16(al, bh3, acc3, 0, 0, 0);
        ah = nah; al = nal;
        bh0 = nbh0; bh1 = nbh1; bh2 = nbh2; bh3 = nbh3;
        bl0 = nbl0; bl1 = nbl1; bl2 = nbl2; bl3 = nbl3;
    }

    const f32x4 accs[4] = {acc0, acc1, acc2, acc3};
#pragma unroll
    for (int t = 0; t < 4; ++t) {
        const int n = (Nt0 + t) * 16 + col;
        const float bn = bias[n];
#pragma unroll
        for (int j = 0; j < 4; ++j) {
            const int m = Mt * 16 + kgrp * 4 + j;
            Y[m * N + n] = accs[t][j] + bn;
        }
    }
}

// XCD-grouping swizzle: l = a + 8b + 64c (a,b in [0,8), c in [0,3))
//  -> Bm = 3a + c (m-strip), Bx = b. Same-Bm blocks share l%8 -> same XCD.
__global__ __launch_bounds__(256) void qkv_kernel(
    const ushort* __restrict__ reh, const ushort* __restrict__ rel,
    const ushort* __restrict__ ceh, const ushort* __restrict__ cel,
    const ushort* __restrict__ wqh, const ushort* __restrict__ wql,
    const ushort* __restrict__ wkh, const ushort* __restrict__ wkl,
    const ushort* __restrict__ wvh, const ushort* __restrict__ wvl,
    const float* __restrict__ bq, const float* __restrict__ bk,
    const float* __restrict__ bv,
    float* __restrict__ Qo, float* __restrict__ Ko, float* __restrict__ Vo)
{
    const int l = blockIdx.x + (blockIdx.y << 3);
    const int Bm = (l & 7) * 3 + (l >> 6);
    const int Bx = (l >> 3) & 7;
    const int Mt = Bm * 4 + (threadIdx.x >> 6);
    const int Nt0 = Bx * 4;
    if (blockIdx.z == 0)      gemm_bf16x3_body(reh, rel, wqh, wql, bq, Qo, Mt, Nt0);
    else if (blockIdx.z == 1) gemm_bf16x3_body(ceh, cel, wkh, wkl, bk, Ko, Mt, Nt0);
    else                      gemm_bf16x3_body(ceh, cel, wvh, wvl, bv, Vo, Mt, Nt0);
}

__global__ __launch_bounds__(256) void oproj_kernel(
    const ushort* __restrict__ hbh, const ushort* __restrict__ hbl,
    const ushort* __restrict__ woh, const ushort* __restrict__ wol,
    const float* __restrict__ bo, float* __restrict__ out)
{
    const int l = blockIdx.x + (blockIdx.y << 3);
    const int Bm = (l & 7) * 3 + (l >> 6);
    const int Bx = (l >> 3) & 7;
    const int Mt = Bm * 4 + (threadIdx.x >> 6);
    const int Nt0 = Bx * 4;
    gemm_bf16x3_body(hbh, hbl, woh, wol, bo, out, Mt, Nt0);
}

// ---------------------------------------------------------------------------
// Vsum kernel: Vsum[b][h][d] = sum_c V[b][c][h*32+d]. Grid (16,4), 256 thr.
// ---------------------------------------------------------------------------
__global__ __launch_bounds__(256) void vsum_kernel(const float* __restrict__ Vb,
                                                   float* __restrict__ Vsum)
{
    __shared__ float part[8][32];
    const int h = blockIdx.x, b = blockIdx.y;
    const int d = threadIdx.x & 31, g = threadIdx.x >> 5;
    float acc = 0.f;
    for (int c = g; c < CC; c += 8)
        acc += Vb[(b * CC + c) * EE + h * DD + d];
    part[g][d] = acc;
    __syncthreads();
    if (g == 0) {
        float s = 0.f;
#pragma unroll
        for (int gg = 0; gg < 8; ++gg) s += part[gg][d];
        Vsum[(b * HH + h) * DD + d] = s;
    }
}

// ---------------------------------------------------------------------------
// Edge precompute: one wave per (b,r). Ballot-compacted edge lists to ws.
// ---------------------------------------------------------------------------
__global__ __launch_bounds__(64) void edges_kernel(
    const float* __restrict__ cost,
    int* __restrict__ ecb, float* __restrict__ ecwb, int* __restrict__ nEb)
{
    const int r = blockIdx.x, b = blockIdx.y;
    const int rowIdx = b * RR + r;
    const int lane = threadIdx.x;
    const float* crow = cost + (size_t)rowIdx * CC;
    const unsigned long long prefix = (1ull << lane) - 1ull;
    int nE = 0;
#pragma unroll
    for (int j = 0; j < 6; ++j) {
        const float cw = crow[lane + 64 * j];
        const unsigned long long mk = __ballot(cw > 0.f);
        if (cw > 0.f) {
            const int slot = nE + __popcll(mk & prefix);
            if (slot < MAXE) {
                ecb [rowIdx * MAXE + slot] = lane + 64 * j;
                ecwb[rowIdx * MAXE + slot] = cw;
            }
        }
        nE += __popcll(mk);
    }
    if (lane == 0) nEb[rowIdx] = (nE < MAXE) ? nE : MAXE;
}

// ---------------------------------------------------------------------------
// Edge scorer: dot(q,k) -> per-head 2x16x1 MLP -> p = exp(tanh*10 - 10).
// All q / MLP params come from wave-uniform addresses -> SGPRs.
// ---------------------------------------------------------------------------
__device__ __forceinline__ float score_edge(
    int c, float cw, int b, int h,
    const float* __restrict__ qrow, const float* __restrict__ Kb,
    const float* __restrict__ w10p, const float* __restrict__ w11p,
    const float* __restrict__ b1p, const float* __restrict__ w2p, float b2h)
{
    const float* kp = Kb + ((size_t)b * CC + c) * EE + h * DD;
    float d0 = 0.f, d1 = 0.f, d2 = 0.f, d3 = 0.f;
#pragma unroll
    for (int dq = 0; dq < 8; ++dq) {
        const float4 kv = *(const float4*)(kp + dq * 4);
        d0 = fmaf(qrow[dq * 4 + 0], kv.x, d0);
        d1 = fmaf(qrow[dq * 4 + 1], kv.y, d1);
        d2 = fmaf(qrow[dq * 4 + 2], kv.z, d2);
        d3 = fmaf(qrow[dq * 4 + 3], kv.w, d3);
    }
    const float dot = ((d0 + d1) + (d2 + d3)) * 0.17677669529663687f;
    float l0 = b2h, l1 = 0.f;
#pragma unroll
    for (int mm = 0; mm < 16; mm += 2) {
        const float h0 = fmaf(dot, w10p[mm],     fmaf(cw, w11p[mm],     b1p[mm]));
        const float h1 = fmaf(dot, w10p[mm + 1], fmaf(cw, w11p[mm + 1], b1p[mm + 1]));
        l0 = fmaf(fmaxf(h0, 0.f), w2p[mm],     l0);
        l1 = fmaf(fmaxf(h1, 0.f), w2p[mm + 1], l1);
    }
    // s = tanh(l)*10; p = exp(s-10) = exp(-20/(e^{2l}+1)); bounded (no ovf).
    const float ex = __expf(2.f * (l0 + l1));
    return __expf(-20.f / (ex + 1.f));
}

// ---------------------------------------------------------------------------
// Semi-sparse attention: ONE WAVE per (b,h,r); h,r wave-uniform so Q row and
// MLP params are scalar (SGPR) loads -> ~zero VGPR footprint, no spills.
// Each lane scores one edge (nE<=64 typ.); fixed-max-10 softmax (scores are
// tanh*10 in (-10,10), beta<=10) -> chunks independent, no online rescale.
//   out = (sum_E (p_e - e^{b-10}) V_e + e^{b-10} Vsum) / (sum p + (C-nE) e^{b-10})
// PV: 2 edges/iter via shfl broadcast, coalesced 128B V loads.
// Grid (8, RR, 8): blockIdx.x = (b,hh) -> XCD pin (worked in R6: FETCH -55%).
// ---------------------------------------------------------------------------
__global__ __launch_bounds__(64) void attn_kernel(
    const float* __restrict__ Qb, const float* __restrict__ Kb,
    const float* __restrict__ Vb,
    const int* __restrict__ ecb, const float* __restrict__ ecwb,
    const int* __restrict__ nEb,
    const float* __restrict__ W1, const float* __restrict__ b1,
    const float* __restrict__ W2, const float* __restrict__ b2,
    const float* __restrict__ beta,
    const float* __restrict__ Vsum,
    ushort* __restrict__ Hbh, ushort* __restrict__ Hbl)
{
    const int combo = blockIdx.x;            // 0..7 -> XCD
    const int b = combo >> 1, hh = combo & 1;
    const int r = blockIdx.y;
    const int h = hh * 8 + blockIdx.z;
    const int lane = threadIdx.x;
    const int rowIdx = b * RR + r;

    const int nE = nEb[rowIdx];              // wave-uniform
    const float b2h = b2[h];
    const float betah = beta[h];
    const float ebeta = __expf(betah - 10.f);

    const float* qrow = Qb + (size_t)rowIdx * EE + h * DD;   // uniform -> SGPR
    const float* w10p = W1 + h * 32;
    const float* w11p = W1 + h * 32 + 16;
    const float* b1p  = b1 + h * 16;
    const float* w2p  = W2 + h * 16;

    // ---- scoring: lane e handles edge e (and e+64 in the rare nE>64 case) --
    int c0 = 0, c1 = 0;
    float p0 = 0.f, p1 = 0.f;
    if (lane < nE) {
        c0 = ecb[rowIdx * MAXE + lane];
        const float cw = ecwb[rowIdx * MAXE + lane];
        p0 = score_edge(c0, cw, b, h, qrow, Kb, w10p, w11p, b1p, w2p, b2h);
    }
    if (nE > 64) {                           // wave-uniform rare branch
        const int e1 = lane + 64;
        if (e1 < nE) {
            c1 = ecb[rowIdx * MAXE + e1];
            const float cw = ecwb[rowIdx * MAXE + e1];
            p1 = score_edge(c1, cw, b, h, qrow, Kb, w10p, w11p, b1p, w2p, b2h);
        }
    }

    // ---- Z: full-wave reduce ----
    float Zl = p0 + p1;
#pragma unroll
    for (int off = 1; off < 64; off <<= 1) Zl += __shfl_xor(Zl, off);

    // ---- PV: 2 edges per iter; lanes (half, d) ----
    const int half = lane >> 5, d = lane & 31;
    float acc = 0.f;
    const int lim0 = (nE < 64) ? nE : 64;
    for (int eo = 0; eo < lim0; eo += 2) {
        const int e = eo + half;
        const float pb = __shfl(p0, e & 63);
        const int   ce = __shfl(c0, e & 63);       // c0=0 on invalid lanes: safe
        const float w = (e < lim0) ? (pb - ebeta) : 0.f;
        const float v = Vb[((size_t)b * CC + ce) * EE + h * DD + d];
        acc = fmaf(w, v, acc);
    }
    if (nE > 64) {
        for (int eo = 64; eo < nE; eo += 2) {
            const int e = eo + half;
            const float pb = __shfl(p1, (e - 64) & 63);
            const int   ce = __shfl(c1, (e - 64) & 63);
            const float w = (e < nE) ? (pb - ebeta) : 0.f;
            const float v = Vb[((size_t)b * CC + ce) * EE + h * DD + d];
            acc = fmaf(w, v, acc);
        }
    }
    acc += __shfl_xor(acc, 32);

    // ---- epilogue: background via Vsum, write packed hi/lo bf16 ----
    if (lane < 32) {
        const float Z = Zl + (float)(CC - nE) * ebeta;
        const float inv = 1.f / Z;
        const float vs = Vsum[(b * HH + h) * DD + d];
        const float o = (acc + ebeta * vs) * inv;
        ushort oh, ol;
        split1(o, oh, ol);
        // packed element (rm, k=h*32+d)
        const int rm = rowIdx;
        const int dst = ((rm >> 4) * 16 + h) * 512 + (d >> 3) * 128 + (rm & 15) * 8 + (d & 7);
        Hbh[dst] = oh;
        Hbl[dst] = ol;
    }
}

// ---------------------------------------------------------------------------
extern "C" void kernel_launch(void* const* d_in, const int* in_sizes, int n_in,
                              void* d_out, int out_size, void* d_ws, size_t ws_size,
                              hipStream_t stream)
{
    const float* rowe = (const float*)d_in[0];
    const float* cole = (const float*)d_in[1];
    const float* cost = (const float*)d_in[2];
    const float* Wq   = (const float*)d_in[3];
    const float* bq   = (const float*)d_in[4];
    const float* Wk   = (const float*)d_in[5];
    const float* bk   = (const float*)d_in[6];
    const float* Wv   = (const float*)d_in[7];
    const float* bv   = (const float*)d_in[8];
    const float* Wo   = (const float*)d_in[9];
    const float* bo   = (const float*)d_in[10];
    const float* W1   = (const float*)d_in[11];
    const float* b1   = (const float*)d_in[12];
    const float* W2   = (const float*)d_in[13];
    const float* b2   = (const float*)d_in[14];
    const float* beta = (const float*)d_in[15];
    float* out = (float*)d_out;

    // ---- workspace carve ----
    char* cur = (char*)d_ws;
    float* Qb   = (float*)cur; cur += (size_t)MROWS * EE * 4;
    float* Kb   = (float*)cur; cur += (size_t)MROWS * EE * 4;
    float* Vb   = (float*)cur; cur += (size_t)MROWS * EE * 4;
    float* Vsum = (float*)cur; cur += (size_t)BB * HH * DD * 4;
    ushort* reh = (ushort*)cur; cur += (size_t)MROWS * EE * 2;
    ushort* rel = (ushort*)cur; cur += (size_t)MROWS * EE * 2;
    ushort* ceh = (ushort*)cur; cur += (size_t)MROWS * EE * 2;
    ushort* cel = (ushort*)cur; cur += (size_t)MROWS * EE * 2;
    ushort* wqh = (ushort*)cur; cur += (size_t)EE * EE * 2;
    ushort* wql = (ushort*)cur; cur += (size_t)EE * EE * 2;
    ushort* wkh = (ushort*)cur; cur += (size_t)EE * EE * 2;
    ushort* wkl = (ushort*)cur; cur += (size_t)EE * EE * 2;
    ushort* wvh = (ushort*)cur; cur += (size_t)EE * EE * 2;
    ushort* wvl = (ushort*)cur; cur += (size_t)EE * EE * 2;
    ushort* woh = (ushort*)cur; cur += (size_t)EE * EE * 2;
    ushort* wol = (ushort*)cur; cur += (size_t)EE * EE * 2;
    ushort* hbh = (ushort*)cur; cur += (size_t)MROWS * EE * 2;
    ushort* hbl = (ushort*)cur; cur += (size_t)MROWS * EE * 2;
    int*    ecb = (int*)cur;   cur += (size_t)MROWS * MAXE * 4;
    float* ecwb = (float*)cur; cur += (size_t)MROWS * MAXE * 4;
    int*    nEb = (int*)cur;   cur += (size_t)MROWS * 4;

    split_kernel<<<dim3(768, 6), 256, 0, stream>>>(
        rowe, cole, Wq, Wk, Wv, Wo,
        reh, rel, ceh, cel, wqh, wql, wkh, wkl, wvh, wvl, woh, wol);

    edges_kernel<<<dim3(RR, BB), 64, 0, stream>>>(cost, ecb, ecwb, nEb);

    dim3 g1(8, 24, 3);
    qkv_kernel<<<g1, 256, 0, stream>>>(reh, rel, ceh, cel,
                                       wqh, wql, wkh, wkl, wvh, wvl,
                                       bq, bk, bv, Qb, Kb, Vb);

    dim3 gv(16, 4);
    vsum_kernel<<<gv, 256, 0, stream>>>(Vb, Vsum);

    dim3 g2(8, RR, 8);   // x = (b,hh) -> XCD pin; y = row; z = head-in-half
    attn_kernel<<<g2, 64, 0, stream>>>(Qb, Kb, Vb, ecb, ecwb, nEb,
                                       W1, b1, W2, b2, beta, Vsum, hbh, hbl);

    dim3 g3(8, 24, 1);
    oproj_kernel<<<g3, 256, 0, stream>>>(hbh, hbl, woh, wol, bo, out);
}

// Round 9
// 90.291 us; speedup vs baseline: 1.1720x; 1.0837x over previous
//
#include <hip/hip_runtime.h>

// Problem constants
#define BB 4
#define RR 384
#define CC 384
#define EE 512
#define HH 16
#define DD 32
#define MROWS 1536   // B*R = B*C
#define MAXE 128     // edge-list stride (nE ~ 38 +- 6; 128 = 15 sigma)

typedef __attribute__((ext_vector_type(8))) short bf16x8;   // 8 bf16 = 4 VGPRs
typedef __attribute__((ext_vector_type(4))) float f32x4;

// ---------------------------------------------------------------------------
// f32 -> (hi, lo) bf16 split, RNE both times. x ~= hi + lo with ~2^-16 rel err.
// ---------------------------------------------------------------------------
__device__ __forceinline__ void split1(float x, ushort& h, ushort& l)
{
    const unsigned u = __float_as_uint(x);
    const unsigned r = (u + 0x7fffu + ((u >> 16) & 1u)) >> 16;
    h = (ushort)r;
    const float hf = __uint_as_float(r << 16);
    const float lo = x - hf;
    const unsigned u2 = __float_as_uint(lo);
    l = (ushort)((u2 + 0x7fffu + ((u2 >> 16) & 1u)) >> 16);
}

// Packed fragment address for element (r, k) of a [rows][512] matrix:
// lane l of the wave covering (r-tile, k-tile) reads elems [l*8, l*8+8).
__device__ __forceinline__ int packed_addr(int r, int k)
{
    return ((r >> 4) * 16 + (k >> 5)) * 512 + ((k >> 3) & 3) * 128 + (r & 15) * 8 + (k & 7);
}

// ---------------------------------------------------------------------------
// Split kernel: 6 arrays -> hi/lo bf16 planes in PACKED fragment layout.
// (R7-exact: unfused, edges_kernel separate.)
// ---------------------------------------------------------------------------
__global__ __launch_bounds__(256) void split_kernel(
    const float* __restrict__ rowe, const float* __restrict__ cole,
    const float* __restrict__ Wq, const float* __restrict__ Wk,
    const float* __restrict__ Wv, const float* __restrict__ Wo,
    ushort* __restrict__ reh, ushort* __restrict__ rel,
    ushort* __restrict__ ceh, ushort* __restrict__ cel,
    ushort* __restrict__ wqh, ushort* __restrict__ wql,
    ushort* __restrict__ wkh, ushort* __restrict__ wkl,
    ushort* __restrict__ wvh, ushort* __restrict__ wvl,
    ushort* __restrict__ woh, ushort* __restrict__ wol)
{
    const float* src; ushort* dh; ushort* dl; int n;
    switch (blockIdx.y) {
    case 0: src = rowe; dh = reh; dl = rel; n = MROWS * EE; break;
    case 1: src = cole; dh = ceh; dl = cel; n = MROWS * EE; break;
    case 2: src = Wq;   dh = wqh; dl = wql; n = EE * EE;    break;
    case 3: src = Wk;   dh = wkh; dl = wkl; n = EE * EE;    break;
    case 4: src = Wv;   dh = wvh; dl = wvl; n = EE * EE;    break;
    default: src = Wo;  dh = woh; dl = wol; n = EE * EE;    break;
    }
    const int i4 = blockIdx.x * 256 + threadIdx.x;
    if (i4 * 4 >= n) return;
    const float4 v = ((const float4*)src)[i4];
    ushort4 hs, ls;
    split1(v.x, hs.x, ls.x);
    split1(v.y, hs.y, ls.y);
    split1(v.z, hs.z, ls.z);
    split1(v.w, hs.w, ls.w);
    const int e0 = i4 * 4;
    const int dst = packed_addr(e0 >> 9, e0 & 511);   // (k&7) in {0,4}: aligned
    *(ushort4*)(dh + dst) = hs;
    *(ushort4*)(dl + dst) = ls;
}

// ---------------------------------------------------------------------------
// bf16x3 emulated-f32 GEMM on packed operands.
// ---------------------------------------------------------------------------
__device__ __forceinline__ void gemm_bf16x3_body(
    const ushort* __restrict__ Ahi, const ushort* __restrict__ Alo,
    const ushort* __restrict__ Whi, const ushort* __restrict__ Wlo,
    const float* __restrict__ bias, float* __restrict__ Y,
    int Mt, int Nt0)
{
    constexpr int N = 512;
    const int lane = threadIdx.x & 63;
    const int col = lane & 15, kgrp = lane >> 4;

    const ushort* pah = Ahi + (size_t)Mt * 8192 + lane * 8;
    const ushort* pal = Alo + (size_t)Mt * 8192 + lane * 8;
    const ushort* pbh = Whi + (size_t)Nt0 * 8192 + lane * 8;
    const ushort* pbl = Wlo + (size_t)Nt0 * 8192 + lane * 8;

    f32x4 acc0 = {}, acc1 = {}, acc2 = {}, acc3 = {};

    bf16x8 ah  = *(const bf16x8*)(pah);
    bf16x8 al  = *(const bf16x8*)(pal);
    bf16x8 bh0 = *(const bf16x8*)(pbh);
    bf16x8 bh1 = *(const bf16x8*)(pbh + 8192);
    bf16x8 bh2 = *(const bf16x8*)(pbh + 16384);
    bf16x8 bh3 = *(const bf16x8*)(pbh + 24576);
    bf16x8 bl0 = *(const bf16x8*)(pbl);
    bf16x8 bl1 = *(const bf16x8*)(pbl + 8192);
    bf16x8 bl2 = *(const bf16x8*)(pbl + 16384);
    bf16x8 bl3 = *(const bf16x8*)(pbl + 24576);

#pragma unroll 4
    for (int kt = 0; kt < 16; ++kt) {
        bf16x8 nah = ah, nal = al;
        bf16x8 nbh0 = bh0, nbh1 = bh1, nbh2 = bh2, nbh3 = bh3;
        bf16x8 nbl0 = bl0, nbl1 = bl1, nbl2 = bl2, nbl3 = bl3;
        if (kt < 15) {
            const int ko = (kt + 1) * 512;
            nah  = *(const bf16x8*)(pah + ko);
            nal  = *(const bf16x8*)(pal + ko);
            nbh0 = *(const bf16x8*)(pbh + ko);
            nbh1 = *(const bf16x8*)(pbh + ko + 8192);
            nbh2 = *(const bf16x8*)(pbh + ko + 16384);
            nbh3 = *(const bf16x8*)(pbh + ko + 24576);
            nbl0 = *(const bf16x8*)(pbl + ko);
            nbl1 = *(const bf16x8*)(pbl + ko + 8192);
            nbl2 = *(const bf16x8*)(pbl + ko + 16384);
            nbl3 = *(const bf16x8*)(pbl + ko + 24576);
        }
        acc0 = __builtin_amdgcn_mfma_f32_16x16x32_bf16(ah, bh0, acc0, 0, 0, 0);
        acc0 = __builtin_amdgcn_mfma_f32_16x16x32_bf16(ah, bl0, acc0, 0, 0, 0);
        acc0 = __builtin_amdgcn_mfma_f32_16x16x32_bf16(al, bh0, acc0, 0, 0, 0);
        acc1 = __builtin_amdgcn_mfma_f32_16x16x32_bf16(ah, bh1, acc1, 0, 0, 0);
        acc1 = __builtin_amdgcn_mfma_f32_16x16x32_bf16(ah, bl1, acc1, 0, 0, 0);
        acc1 = __builtin_amdgcn_mfma_f32_16x16x32_bf16(al, bh1, acc1, 0, 0, 0);
        acc2 = __builtin_amdgcn_mfma_f32_16x16x32_bf16(ah, bh2, acc2, 0, 0, 0);
        acc2 = __builtin_amdgcn_mfma_f32_16x16x32_bf16(ah, bl2, acc2, 0, 0, 0);
        acc2 = __builtin_amdgcn_mfma_f32_16x16x32_bf16(al, bh2, acc2, 0, 0, 0);
        acc3 = __builtin_amdgcn_mfma_f32_16x16x32_bf16(ah, bh3, acc3, 0, 0, 0);
        acc3 = __builtin_amdgcn_mfma_f32_16x16x32_bf16(ah, bl3, acc3, 0, 0, 0);
        acc3 = __builtin_amdgcn_mfma_f32_16x16x32_bf16(al, bh3, acc3, 0, 0, 0);
        ah = nah; al = nal;
        bh0 = nbh0; bh1 = nbh1; bh2 = nbh2; bh3 = nbh3;
        bl0 = nbl0; bl1 = nbl1; bl2 = nbl2; bl3 = nbl3;
    }

    const f32x4 accs[4] = {acc0, acc1, acc2, acc3};
#pragma unroll
    for (int t = 0; t < 4; ++t) {
        const int n = (Nt0 + t) * 16 + col;
        const float bn = bias[n];
#pragma unroll
        for (int j = 0; j < 4; ++j) {
            const int m = Mt * 16 + kgrp * 4 + j;
            Y[m * N + n] = accs[t][j] + bn;
        }
    }
}

// XCD-grouping swizzle: l = a + 8b + 64c (a,b in [0,8), c in [0,3))
//  -> Bm = 3a + c (m-strip), Bx = b. Same-Bm blocks share l%8 -> same XCD.
__global__ __launch_bounds__(256) void qkv_kernel(
    const ushort* __restrict__ reh, const ushort* __restrict__ rel,
    const ushort* __restrict__ ceh, const ushort* __restrict__ cel,
    const ushort* __restrict__ wqh, const ushort* __restrict__ wql,
    const ushort* __restrict__ wkh, const ushort* __restrict__ wkl,
    const ushort* __restrict__ wvh, const ushort* __restrict__ wvl,
    const float* __restrict__ bq, const float* __restrict__ bk,
    const float* __restrict__ bv,
    float* __restrict__ Qo, float* __restrict__ Ko, float* __restrict__ Vo)
{
    const int l = blockIdx.x + (blockIdx.y << 3);
    const int Bm = (l & 7) * 3 + (l >> 6);
    const int Bx = (l >> 3) & 7;
    const int Mt = Bm * 4 + (threadIdx.x >> 6);
    const int Nt0 = Bx * 4;
    if (blockIdx.z == 0)      gemm_bf16x3_body(reh, rel, wqh, wql, bq, Qo, Mt, Nt0);
    else if (blockIdx.z == 1) gemm_bf16x3_body(ceh, cel, wkh, wkl, bk, Ko, Mt, Nt0);
    else                      gemm_bf16x3_body(ceh, cel, wvh, wvl, bv, Vo, Mt, Nt0);
}

__global__ __launch_bounds__(256) void oproj_kernel(
    const ushort* __restrict__ hbh, const ushort* __restrict__ hbl,
    const ushort* __restrict__ woh, const ushort* __restrict__ wol,
    const float* __restrict__ bo, float* __restrict__ out)
{
    const int l = blockIdx.x + (blockIdx.y << 3);
    const int Bm = (l & 7) * 3 + (l >> 6);
    const int Bx = (l >> 3) & 7;
    const int Mt = Bm * 4 + (threadIdx.x >> 6);
    const int Nt0 = Bx * 4;
    gemm_bf16x3_body(hbh, hbl, woh, wol, bo, out, Mt, Nt0);
}

// ---------------------------------------------------------------------------
// Vsum kernel: Vsum[b][h][d] = sum_c V[b][c][h*32+d]. Grid (16,4), 256 thr.
// ---------------------------------------------------------------------------
__global__ __launch_bounds__(256) void vsum_kernel(const float* __restrict__ Vb,
                                                   float* __restrict__ Vsum)
{
    __shared__ float part[8][32];
    const int h = blockIdx.x, b = blockIdx.y;
    const int d = threadIdx.x & 31, g = threadIdx.x >> 5;
    float acc = 0.f;
    for (int c = g; c < CC; c += 8)
        acc += Vb[(b * CC + c) * EE + h * DD + d];
    part[g][d] = acc;
    __syncthreads();
    if (g == 0) {
        float s = 0.f;
#pragma unroll
        for (int gg = 0; gg < 8; ++gg) s += part[gg][d];
        Vsum[(b * HH + h) * DD + d] = s;
    }
}

// ---------------------------------------------------------------------------
// Edge precompute: one wave per (b,r). Ballot-compacted edge lists to ws.
// (R7-exact standalone kernel.)
// ---------------------------------------------------------------------------
__global__ __launch_bounds__(64) void edges_kernel(
    const float* __restrict__ cost,
    int* __restrict__ ecb, float* __restrict__ ecwb, int* __restrict__ nEb)
{
    const int r = blockIdx.x, b = blockIdx.y;
    const int rowIdx = b * RR + r;
    const int lane = threadIdx.x;
    const float* crow = cost + (size_t)rowIdx * CC;
    const unsigned long long prefix = (1ull << lane) - 1ull;
    int nE = 0;
#pragma unroll
    for (int j = 0; j < 6; ++j) {
        const float cw = crow[lane + 64 * j];
        const unsigned long long mk = __ballot(cw > 0.f);
        if (cw > 0.f) {
            const int slot = nE + __popcll(mk & prefix);
            if (slot < MAXE) {
                ecb [rowIdx * MAXE + slot] = lane + 64 * j;
                ecwb[rowIdx * MAXE + slot] = cw;
            }
        }
        nE += __popcll(mk);
    }
    if (lane == 0) nEb[rowIdx] = (nE < MAXE) ? nE : MAXE;
}

// ---------------------------------------------------------------------------
// Edge scorer: dot(q,k) -> per-head 2x16x1 MLP -> p = exp(tanh*10 - 10).
// All q / MLP params come from wave-uniform addresses -> SGPRs.
// ---------------------------------------------------------------------------
__device__ __forceinline__ float score_edge(
    int c, float cw, int b, int h,
    const float* __restrict__ qrow, const float* __restrict__ Kb,
    const float* __restrict__ w10p, const float* __restrict__ w11p,
    const float* __restrict__ b1p, const float* __restrict__ w2p, float b2h)
{
    const float* kp = Kb + ((size_t)b * CC + c) * EE + h * DD;
    float d0 = 0.f, d1 = 0.f, d2 = 0.f, d3 = 0.f;
#pragma unroll
    for (int dq = 0; dq < 8; ++dq) {
        const float4 kv = *(const float4*)(kp + dq * 4);
        d0 = fmaf(qrow[dq * 4 + 0], kv.x, d0);
        d1 = fmaf(qrow[dq * 4 + 1], kv.y, d1);
        d2 = fmaf(qrow[dq * 4 + 2], kv.z, d2);
        d3 = fmaf(qrow[dq * 4 + 3], kv.w, d3);
    }
    const float dot = ((d0 + d1) + (d2 + d3)) * 0.17677669529663687f;
    float l0 = b2h, l1 = 0.f;
#pragma unroll
    for (int mm = 0; mm < 16; mm += 2) {
        const float h0 = fmaf(dot, w10p[mm],     fmaf(cw, w11p[mm],     b1p[mm]));
        const float h1 = fmaf(dot, w10p[mm + 1], fmaf(cw, w11p[mm + 1], b1p[mm + 1]));
        l0 = fmaf(fmaxf(h0, 0.f), w2p[mm],     l0);
        l1 = fmaf(fmaxf(h1, 0.f), w2p[mm + 1], l1);
    }
    // s = tanh(l)*10; p = exp(s-10) = exp(-20/(e^{2l}+1)); bounded (no ovf).
    const float ex = __expf(2.f * (l0 + l1));
    return __expf(-20.f / (ex + 1.f));
}

// ---------------------------------------------------------------------------
// Semi-sparse attention: ONE WAVE per (b, r, head-PAIR). R7's proven 1-wave
// block shape (passed post-timing twice); ILP doubled by processing heads
// h0 and h0+1 in the same wave: 2 independent score chains + 2 independent
// PV load/FMA chains hide latency at the same 16-wave/CU occupancy.
// Fixed-max-10 softmax (scores tanh*10 in (-10,10), beta<=10):
//   out = (sum_E (p_e - e^{b-10}) V_e + e^{b-10} Vsum) / (sum p + (C-nE) e^{b-10})
// Grid (8, RR, 4): blockIdx.x = (b,hh) -> XCD pin (R6: FETCH -55%).
// ---------------------------------------------------------------------------
__global__ __launch_bounds__(64) void attn_kernel(
    const float* __restrict__ Qb, const float* __restrict__ Kb,
    const float* __restrict__ Vb,
    const int* __restrict__ ecb, const float* __restrict__ ecwb,
    const int* __restrict__ nEb,
    const float* __restrict__ W1, const float* __restrict__ b1,
    const float* __restrict__ W2, const float* __restrict__ b2,
    const float* __restrict__ beta,
    const float* __restrict__ Vsum,
    ushort* __restrict__ Hbh, ushort* __restrict__ Hbl)
{
    const int combo = blockIdx.x;            // 0..7 -> XCD
    const int b = combo >> 1, hh = combo & 1;
    const int r = blockIdx.y;
    const int h0 = hh * 8 + blockIdx.z * 2;  // this wave: heads h0, h0+1
    const int lane = threadIdx.x;
    const int rowIdx = b * RR + r;

    const int nE = nEb[rowIdx];              // wave-uniform
    const float b2h0 = b2[h0], b2h1 = b2[h0 + 1];
    const float ebeta0 = __expf(beta[h0] - 10.f);
    const float ebeta1 = __expf(beta[h0 + 1] - 10.f);

    const float* qrow0 = Qb + (size_t)rowIdx * EE + h0 * DD;   // uniform -> SGPR
    const float* qrow1 = qrow0 + DD;
    const float* w10p0 = W1 + h0 * 32;       const float* w10p1 = w10p0 + 32;
    const float* w11p0 = W1 + h0 * 32 + 16;  const float* w11p1 = w11p0 + 32;
    const float* b1p0  = b1 + h0 * 16;       const float* b1p1  = b1p0 + 16;
    const float* w2p0  = W2 + h0 * 16;       const float* w2p1  = w2p0 + 16;

    // ---- scoring: lane e = edge e, both heads (independent chains) ----
    int c0 = 0, c1 = 0;
    float pA0 = 0.f, pB0 = 0.f, pA1 = 0.f, pB1 = 0.f;
    if (lane < nE) {
        c0 = ecb[rowIdx * MAXE + lane];
        const float cw = ecwb[rowIdx * MAXE + lane];
        pA0 = score_edge(c0, cw, b, h0,     qrow0, Kb, w10p0, w11p0, b1p0, w2p0, b2h0);
        pB0 = score_edge(c0, cw, b, h0 + 1, qrow1, Kb, w10p1, w11p1, b1p1, w2p1, b2h1);
    }
    if (nE > 64) {                           // wave-uniform rare branch
        const int e1 = lane + 64;
        if (e1 < nE) {
            c1 = ecb[rowIdx * MAXE + e1];
            const float cw = ecwb[rowIdx * MAXE + e1];
            pA1 = score_edge(c1, cw, b, h0,     qrow0, Kb, w10p0, w11p0, b1p0, w2p0, b2h0);
            pB1 = score_edge(c1, cw, b, h0 + 1, qrow1, Kb, w10p1, w11p1, b1p1, w2p1, b2h1);
        }
    }

    // ---- Z: full-wave reduce, both heads ----
    float ZA = pA0 + pA1, ZB = pB0 + pB1;
#pragma unroll
    for (int off = 1; off < 64; off <<= 1) {
        ZA += __shfl_xor(ZA, off);
        ZB += __shfl_xor(ZB, off);
    }

    // ---- PV: 2 edges/iter, 2 heads -> 2 loads + 2 FMA chains in flight ----
    const int half = lane >> 5, d = lane & 31;
    const float wA0 = pA0 - ebeta0, wB0 = pB0 - ebeta1;
    float accA = 0.f, accB = 0.f;
    const int lim0 = (nE < 64) ? nE : 64;
    for (int eo = 0; eo < lim0; eo += 2) {
        const int e = eo + half;
        const float wa = __shfl(wA0, e & 63);
        const float wb = __shfl(wB0, e & 63);
        const int   ce = __shfl(c0, e & 63);   // c0=0 on invalid lanes: safe
        const bool ok = e < lim0;
        const size_t vb0 = ((size_t)b * CC + ce) * EE + h0 * DD + d;
        const float vA = Vb[vb0];
        const float vB = Vb[vb0 + DD];
        accA = fmaf(ok ? wa : 0.f, vA, accA);
        accB = fmaf(ok ? wb : 0.f, vB, accB);
    }
    if (nE > 64) {
        const float wA1 = pA1 - ebeta0, wB1 = pB1 - ebeta1;
        for (int eo = 64; eo < nE; eo += 2) {
            const int e = eo + half;
            const float wa = __shfl(wA1, (e - 64) & 63);
            const float wb = __shfl(wB1, (e - 64) & 63);
            const int   ce = __shfl(c1, (e - 64) & 63);
            const bool ok = e < nE;
            const size_t vb0 = ((size_t)b * CC + ce) * EE + h0 * DD + d;
            const float vA = Vb[vb0];
            const float vB = Vb[vb0 + DD];
            accA = fmaf(ok ? wa : 0.f, vA, accA);
            accB = fmaf(ok ? wb : 0.f, vB, accB);
        }
    }
    accA += __shfl_xor(accA, 32);
    accB += __shfl_xor(accB, 32);

    // ---- epilogue: background via Vsum, write packed hi/lo bf16 ----
    if (lane < 32) {
        const float invA = 1.f / (ZA + (float)(CC - nE) * ebeta0);
        const float invB = 1.f / (ZB + (float)(CC - nE) * ebeta1);
        const float vsA = Vsum[(b * HH + h0) * DD + d];
        const float vsB = Vsum[(b * HH + h0 + 1) * DD + d];
        const float oA = (accA + ebeta0 * vsA) * invA;
        const float oB = (accB + ebeta1 * vsB) * invB;
        const int rm = rowIdx;
        const int base_in = (d >> 3) * 128 + (rm & 15) * 8 + (d & 7);
        ushort oh, ol;
        split1(oA, oh, ol);
        int dst = ((rm >> 4) * 16 + h0) * 512 + base_in;
        Hbh[dst] = oh; Hbl[dst] = ol;
        split1(oB, oh, ol);
        dst = ((rm >> 4) * 16 + h0 + 1) * 512 + base_in;
        Hbh[dst] = oh; Hbl[dst] = ol;
    }
}

// ---------------------------------------------------------------------------
extern "C" void kernel_launch(void* const* d_in, const int* in_sizes, int n_in,
                              void* d_out, int out_size, void* d_ws, size_t ws_size,
                              hipStream_t stream)
{
    const float* rowe = (const float*)d_in[0];
    const float* cole = (const float*)d_in[1];
    const float* cost = (const float*)d_in[2];
    const float* Wq   = (const float*)d_in[3];
    const float* bq   = (const float*)d_in[4];
    const float* Wk   = (const float*)d_in[5];
    const float* bk   = (const float*)d_in[6];
    const float* Wv   = (const float*)d_in[7];
    const float* bv   = (const float*)d_in[8];
    const float* Wo   = (const float*)d_in[9];
    const float* bo   = (const float*)d_in[10];
    const float* W1   = (const float*)d_in[11];
    const float* b1   = (const float*)d_in[12];
    const float* W2   = (const float*)d_in[13];
    const float* b2   = (const float*)d_in[14];
    const float* beta = (const float*)d_in[15];
    float* out = (float*)d_out;

    // ---- workspace carve ----
    char* cur = (char*)d_ws;
    float* Qb   = (float*)cur; cur += (size_t)MROWS * EE * 4;
    float* Kb   = (float*)cur; cur += (size_t)MROWS * EE * 4;
    float* Vb   = (float*)cur; cur += (size_t)MROWS * EE * 4;
    float* Vsum = (float*)cur; cur += (size_t)BB * HH * DD * 4;
    ushort* reh = (ushort*)cur; cur += (size_t)MROWS * EE * 2;
    ushort* rel = (ushort*)cur; cur += (size_t)MROWS * EE * 2;
    ushort* ceh = (ushort*)cur; cur += (size_t)MROWS * EE * 2;
    ushort* cel = (ushort*)cur; cur += (size_t)MROWS * EE * 2;
    ushort* wqh = (ushort*)cur; cur += (size_t)EE * EE * 2;
    ushort* wql = (ushort*)cur; cur += (size_t)EE * EE * 2;
    ushort* wkh = (ushort*)cur; cur += (size_t)EE * EE * 2;
    ushort* wkl = (ushort*)cur; cur += (size_t)EE * EE * 2;
    ushort* wvh = (ushort*)cur; cur += (size_t)EE * EE * 2;
    ushort* wvl = (ushort*)cur; cur += (size_t)EE * EE * 2;
    ushort* woh = (ushort*)cur; cur += (size_t)EE * EE * 2;
    ushort* wol = (ushort*)cur; cur += (size_t)EE * EE * 2;
    ushort* hbh = (ushort*)cur; cur += (size_t)MROWS * EE * 2;
    ushort* hbl = (ushort*)cur; cur += (size_t)MROWS * EE * 2;
    int*    ecb = (int*)cur;   cur += (size_t)MROWS * MAXE * 4;
    float* ecwb = (float*)cur; cur += (size_t)MROWS * MAXE * 4;
    int*    nEb = (int*)cur;   cur += (size_t)MROWS * 4;

    split_kernel<<<dim3(768, 6), 256, 0, stream>>>(
        rowe, cole, Wq, Wk, Wv, Wo,
        reh, rel, ceh, cel, wqh, wql, wkh, wkl, wvh, wvl, woh, wol);

    edges_kernel<<<dim3(RR, BB), 64, 0, stream>>>(cost, ecb, ecwb, nEb);

    dim3 g1(8, 24, 3);
    qkv_kernel<<<g1, 256, 0, stream>>>(reh, rel, ceh, cel,
                                       wqh, wql, wkh, wkl, wvh, wvl,
                                       bq, bk, bv, Qb, Kb, Vb);

    dim3 gv(16, 4);
    vsum_kernel<<<gv, 256, 0, stream>>>(Vb, Vsum);

    dim3 g2(8, RR, 4);   // x = (b,hh) -> XCD pin; y = row; z = head-pair
    attn_kernel<<<g2, 64, 0, stream>>>(Qb, Kb, Vb, ecb, ecwb, nEb,
                                       W1, b1, W2, b2, beta, Vsum, hbh, hbl);

    dim3 g3(8, 24, 1);
    oproj_kernel<<<g3, 256, 0, stream>>>(hbh, hbl, woh, wol, bo, out);
}

// Round 10
// 88.096 us; speedup vs baseline: 1.2012x; 1.0249x over previous
//
#include <hip/hip_runtime.h>

// Problem constants
#define BB 4
#define RR 384
#define CC 384
#define EE 512
#define HH 16
#define DD 32
#define MROWS 1536   // B*R = B*C
#define MAXE 128     // edge-list stride (nE ~ 38 +- 6; 128 = 15 sigma)

typedef __attribute__((ext_vector_type(8))) short bf16x8;   // 8 bf16 = 4 VGPRs
typedef __attribute__((ext_vector_type(4))) float f32x4;

// ---------------------------------------------------------------------------
// f32 -> (hi, lo) bf16 split, RNE both times. x ~= hi + lo with ~2^-16 rel err.
// ---------------------------------------------------------------------------
__device__ __forceinline__ void split1(float x, ushort& h, ushort& l)
{
    const unsigned u = __float_as_uint(x);
    const unsigned r = (u + 0x7fffu + ((u >> 16) & 1u)) >> 16;
    h = (ushort)r;
    const float hf = __uint_as_float(r << 16);
    const float lo = x - hf;
    const unsigned u2 = __float_as_uint(lo);
    l = (ushort)((u2 + 0x7fffu + ((u2 >> 16) & 1u)) >> 16);
}

// Packed fragment address for element (r, k) of a [rows][512] matrix:
// lane l of the wave covering (r-tile, k-tile) reads elems [l*8, l*8+8).
__device__ __forceinline__ int packed_addr(int r, int k)
{
    return ((r >> 4) * 16 + (k >> 5)) * 512 + ((k >> 3) & 3) * 128 + (r & 15) * 8 + (k & 7);
}

// ---------------------------------------------------------------------------
// Split kernel: 6 arrays -> hi/lo bf16 planes in PACKED fragment layout.
// ---------------------------------------------------------------------------
__global__ __launch_bounds__(256) void split_kernel(
    const float* __restrict__ rowe, const float* __restrict__ cole,
    const float* __restrict__ Wq, const float* __restrict__ Wk,
    const float* __restrict__ Wv, const float* __restrict__ Wo,
    ushort* __restrict__ reh, ushort* __restrict__ rel,
    ushort* __restrict__ ceh, ushort* __restrict__ cel,
    ushort* __restrict__ wqh, ushort* __restrict__ wql,
    ushort* __restrict__ wkh, ushort* __restrict__ wkl,
    ushort* __restrict__ wvh, ushort* __restrict__ wvl,
    ushort* __restrict__ woh, ushort* __restrict__ wol)
{
    const float* src; ushort* dh; ushort* dl; int n;
    switch (blockIdx.y) {
    case 0: src = rowe; dh = reh; dl = rel; n = MROWS * EE; break;
    case 1: src = cole; dh = ceh; dl = cel; n = MROWS * EE; break;
    case 2: src = Wq;   dh = wqh; dl = wql; n = EE * EE;    break;
    case 3: src = Wk;   dh = wkh; dl = wkl; n = EE * EE;    break;
    case 4: src = Wv;   dh = wvh; dl = wvl; n = EE * EE;    break;
    default: src = Wo;  dh = woh; dl = wol; n = EE * EE;    break;
    }
    const int i4 = blockIdx.x * 256 + threadIdx.x;
    if (i4 * 4 >= n) return;
    const float4 v = ((const float4*)src)[i4];
    ushort4 hs, ls;
    split1(v.x, hs.x, ls.x);
    split1(v.y, hs.y, ls.y);
    split1(v.z, hs.z, ls.z);
    split1(v.w, hs.w, ls.w);
    const int e0 = i4 * 4;
    const int dst = packed_addr(e0 >> 9, e0 & 511);   // (k&7) in {0,4}: aligned
    *(ushort4*)(dh + dst) = hs;
    *(ushort4*)(dl + dst) = ls;
}

// ---------------------------------------------------------------------------
// bf16x3 emulated-f32 GEMM on packed operands.
// ---------------------------------------------------------------------------
__device__ __forceinline__ void gemm_bf16x3_body(
    const ushort* __restrict__ Ahi, const ushort* __restrict__ Alo,
    const ushort* __restrict__ Whi, const ushort* __restrict__ Wlo,
    const float* __restrict__ bias, float* __restrict__ Y,
    int Mt, int Nt0)
{
    constexpr int N = 512;
    const int lane = threadIdx.x & 63;
    const int col = lane & 15, kgrp = lane >> 4;

    const ushort* pah = Ahi + (size_t)Mt * 8192 + lane * 8;
    const ushort* pal = Alo + (size_t)Mt * 8192 + lane * 8;
    const ushort* pbh = Whi + (size_t)Nt0 * 8192 + lane * 8;
    const ushort* pbl = Wlo + (size_t)Nt0 * 8192 + lane * 8;

    f32x4 acc0 = {}, acc1 = {}, acc2 = {}, acc3 = {};

    bf16x8 ah  = *(const bf16x8*)(pah);
    bf16x8 al  = *(const bf16x8*)(pal);
    bf16x8 bh0 = *(const bf16x8*)(pbh);
    bf16x8 bh1 = *(const bf16x8*)(pbh + 8192);
    bf16x8 bh2 = *(const bf16x8*)(pbh + 16384);
    bf16x8 bh3 = *(const bf16x8*)(pbh + 24576);
    bf16x8 bl0 = *(const bf16x8*)(pbl);
    bf16x8 bl1 = *(const bf16x8*)(pbl + 8192);
    bf16x8 bl2 = *(const bf16x8*)(pbl + 16384);
    bf16x8 bl3 = *(const bf16x8*)(pbl + 24576);

#pragma unroll 4
    for (int kt = 0; kt < 16; ++kt) {
        bf16x8 nah = ah, nal = al;
        bf16x8 nbh0 = bh0, nbh1 = bh1, nbh2 = bh2, nbh3 = bh3;
        bf16x8 nbl0 = bl0, nbl1 = bl1, nbl2 = bl2, nbl3 = bl3;
        if (kt < 15) {
            const int ko = (kt + 1) * 512;
            nah  = *(const bf16x8*)(pah + ko);
            nal  = *(const bf16x8*)(pal + ko);
            nbh0 = *(const bf16x8*)(pbh + ko);
            nbh1 = *(const bf16x8*)(pbh + ko + 8192);
            nbh2 = *(const bf16x8*)(pbh + ko + 16384);
            nbh3 = *(const bf16x8*)(pbh + ko + 24576);
            nbl0 = *(const bf16x8*)(pbl + ko);
            nbl1 = *(const bf16x8*)(pbl + ko + 8192);
            nbl2 = *(const bf16x8*)(pbl + ko + 16384);
            nbl3 = *(const bf16x8*)(pbl + ko + 24576);
        }
        acc0 = __builtin_amdgcn_mfma_f32_16x16x32_bf16(ah, bh0, acc0, 0, 0, 0);
        acc0 = __builtin_amdgcn_mfma_f32_16x16x32_bf16(ah, bl0, acc0, 0, 0, 0);
        acc0 = __builtin_amdgcn_mfma_f32_16x16x32_bf16(al, bh0, acc0, 0, 0, 0);
        acc1 = __builtin_amdgcn_mfma_f32_16x16x32_bf16(ah, bh1, acc1, 0, 0, 0);
        acc1 = __builtin_amdgcn_mfma_f32_16x16x32_bf16(ah, bl1, acc1, 0, 0, 0);
        acc1 = __builtin_amdgcn_mfma_f32_16x16x32_bf16(al, bh1, acc1, 0, 0, 0);
        acc2 = __builtin_amdgcn_mfma_f32_16x16x32_bf16(ah, bh2, acc2, 0, 0, 0);
        acc2 = __builtin_amdgcn_mfma_f32_16x16x32_bf16(ah, bl2, acc2, 0, 0, 0);
        acc2 = __builtin_amdgcn_mfma_f32_16x16x32_bf16(al, bh2, acc2, 0, 0, 0);
        acc3 = __builtin_amdgcn_mfma_f32_16x16x32_bf16(ah, bh3, acc3, 0, 0, 0);
        acc3 = __builtin_amdgcn_mfma_f32_16x16x32_bf16(ah, bl3, acc3, 0, 0, 0);
        acc3 = __builtin_amdgcn_mfma_f32_16x16x32_bf16(al, bh3, acc3, 0, 0, 0);
        ah = nah; al = nal;
        bh0 = nbh0; bh1 = nbh1; bh2 = nbh2; bh3 = nbh3;
        bl0 = nbl0; bl1 = nbl1; bl2 = nbl2; bl3 = nbl3;
    }

    const f32x4 accs[4] = {acc0, acc1, acc2, acc3};
#pragma unroll
    for (int t = 0; t < 4; ++t) {
        const int n = (Nt0 + t) * 16 + col;
        const float bn = bias[n];
#pragma unroll
        for (int j = 0; j < 4; ++j) {
            const int m = Mt * 16 + kgrp * 4 + j;
            Y[m * N + n] = accs[t][j] + bn;
        }
    }
}

// XCD-grouping swizzle: l = a + 8b + 64c (a,b in [0,8), c in [0,3))
//  -> Bm = 3a + c (m-strip), Bx = b. Same-Bm blocks share l%8 -> same XCD.
__global__ __launch_bounds__(256) void qkv_kernel(
    const ushort* __restrict__ reh, const ushort* __restrict__ rel,
    const ushort* __restrict__ ceh, const ushort* __restrict__ cel,
    const ushort* __restrict__ wqh, const ushort* __restrict__ wql,
    const ushort* __restrict__ wkh, const ushort* __restrict__ wkl,
    const ushort* __restrict__ wvh, const ushort* __restrict__ wvl,
    const float* __restrict__ bq, const float* __restrict__ bk,
    const float* __restrict__ bv,
    float* __restrict__ Qo, float* __restrict__ Ko, float* __restrict__ Vo)
{
    const int l = blockIdx.x + (blockIdx.y << 3);
    const int Bm = (l & 7) * 3 + (l >> 6);
    const int Bx = (l >> 3) & 7;
    const int Mt = Bm * 4 + (threadIdx.x >> 6);
    const int Nt0 = Bx * 4;
    if (blockIdx.z == 0)      gemm_bf16x3_body(reh, rel, wqh, wql, bq, Qo, Mt, Nt0);
    else if (blockIdx.z == 1) gemm_bf16x3_body(ceh, cel, wkh, wkl, bk, Ko, Mt, Nt0);
    else                      gemm_bf16x3_body(ceh, cel, wvh, wvl, bv, Vo, Mt, Nt0);
}

__global__ __launch_bounds__(256) void oproj_kernel(
    const ushort* __restrict__ hbh, const ushort* __restrict__ hbl,
    const ushort* __restrict__ woh, const ushort* __restrict__ wol,
    const float* __restrict__ bo, float* __restrict__ out)
{
    const int l = blockIdx.x + (blockIdx.y << 3);
    const int Bm = (l & 7) * 3 + (l >> 6);
    const int Bx = (l >> 3) & 7;
    const int Mt = Bm * 4 + (threadIdx.x >> 6);
    const int Nt0 = Bx * 4;
    gemm_bf16x3_body(hbh, hbl, woh, wol, bo, out, Mt, Nt0);
}

// ---------------------------------------------------------------------------
// Vsum kernel: Vsum[b][h][d] = sum_c V[b][c][h*32+d]. Grid (16,4), 256 thr.
// ---------------------------------------------------------------------------
__global__ __launch_bounds__(256) void vsum_kernel(const float* __restrict__ Vb,
                                                   float* __restrict__ Vsum)
{
    __shared__ float part[8][32];
    const int h = blockIdx.x, b = blockIdx.y;
    const int d = threadIdx.x & 31, g = threadIdx.x >> 5;
    float acc = 0.f;
    for (int c = g; c < CC; c += 8)
        acc += Vb[(b * CC + c) * EE + h * DD + d];
    part[g][d] = acc;
    __syncthreads();
    if (g == 0) {
        float s = 0.f;
#pragma unroll
        for (int gg = 0; gg < 8; ++gg) s += part[gg][d];
        Vsum[(b * HH + h) * DD + d] = s;
    }
}

// ---------------------------------------------------------------------------
// Edge precompute: one wave per (b,r). Ballot-compacted edge lists to ws.
// ---------------------------------------------------------------------------
__global__ __launch_bounds__(64) void edges_kernel(
    const float* __restrict__ cost,
    int* __restrict__ ecb, float* __restrict__ ecwb, int* __restrict__ nEb)
{
    const int r = blockIdx.x, b = blockIdx.y;
    const int rowIdx = b * RR + r;
    const int lane = threadIdx.x;
    const float* crow = cost + (size_t)rowIdx * CC;
    const unsigned long long prefix = (1ull << lane) - 1ull;
    int nE = 0;
#pragma unroll
    for (int j = 0; j < 6; ++j) {
        const float cw = crow[lane + 64 * j];
        const unsigned long long mk = __ballot(cw > 0.f);
        if (cw > 0.f) {
            const int slot = nE + __popcll(mk & prefix);
            if (slot < MAXE) {
                ecb [rowIdx * MAXE + slot] = lane + 64 * j;
                ecwb[rowIdx * MAXE + slot] = cw;
            }
        }
        nE += __popcll(mk);
    }
    if (lane == 0) nEb[rowIdx] = (nE < MAXE) ? nE : MAXE;
}

// ---------------------------------------------------------------------------
// Edge scorer: dot(q,k) -> per-head 2x16x1 MLP -> p = exp(tanh*10 - 10).
// All q / MLP params come from wave-uniform addresses -> SGPRs.
// ---------------------------------------------------------------------------
__device__ __forceinline__ float score_edge(
    int c, float cw, int b, int h,
    const float* __restrict__ qrow, const float* __restrict__ Kb,
    const float* __restrict__ w10p, const float* __restrict__ w11p,
    const float* __restrict__ b1p, const float* __restrict__ w2p, float b2h)
{
    const float* kp = Kb + ((size_t)b * CC + c) * EE + h * DD;
    float d0 = 0.f, d1 = 0.f, d2 = 0.f, d3 = 0.f;
#pragma unroll
    for (int dq = 0; dq < 8; ++dq) {
        const float4 kv = *(const float4*)(kp + dq * 4);
        d0 = fmaf(qrow[dq * 4 + 0], kv.x, d0);
        d1 = fmaf(qrow[dq * 4 + 1], kv.y, d1);
        d2 = fmaf(qrow[dq * 4 + 2], kv.z, d2);
        d3 = fmaf(qrow[dq * 4 + 3], kv.w, d3);
    }
    const float dot = ((d0 + d1) + (d2 + d3)) * 0.17677669529663687f;
    float l0 = b2h, l1 = 0.f;
#pragma unroll
    for (int mm = 0; mm < 16; mm += 2) {
        const float h0 = fmaf(dot, w10p[mm],     fmaf(cw, w11p[mm],     b1p[mm]));
        const float h1 = fmaf(dot, w10p[mm + 1], fmaf(cw, w11p[mm + 1], b1p[mm + 1]));
        l0 = fmaf(fmaxf(h0, 0.f), w2p[mm],     l0);
        l1 = fmaf(fmaxf(h1, 0.f), w2p[mm + 1], l1);
    }
    // s = tanh(l)*10; p = exp(s-10) = exp(-20/(e^{2l}+1)); bounded (no ovf).
    const float ex = __expf(2.f * (l0 + l1));
    return __expf(-20.f / (ex + 1.f));
}

// ---------------------------------------------------------------------------
// Semi-sparse attention: ONE WAVE per (b, r, head-QUAD). R9's proven 1-wave
// structure with ILP extended 2->4 heads: 4 independent score chains and
// 4 independent PV load/FMA chains per wave at unchanged occupancy (the
// 16-workgroup/CU cap binds, not VGPRs).
// Fixed-max-10 softmax (scores tanh*10 in (-10,10), beta<=10):
//   out = (sum_E (p_e - e^{b-10}) V_e + e^{b-10} Vsum) / (sum p + (C-nE) e^{b-10})
// Grid (8, RR, 2): blockIdx.x = (b,hh) -> XCD pin (R6: FETCH -55%).
// ---------------------------------------------------------------------------
__global__ __launch_bounds__(64) void attn_kernel(
    const float* __restrict__ Qb, const float* __restrict__ Kb,
    const float* __restrict__ Vb,
    const int* __restrict__ ecb, const float* __restrict__ ecwb,
    const int* __restrict__ nEb,
    const float* __restrict__ W1, const float* __restrict__ b1,
    const float* __restrict__ W2, const float* __restrict__ b2,
    const float* __restrict__ beta,
    const float* __restrict__ Vsum,
    ushort* __restrict__ Hbh, ushort* __restrict__ Hbl)
{
    const int combo = blockIdx.x;            // 0..7 -> XCD
    const int b = combo >> 1, hh = combo & 1;
    const int r = blockIdx.y;
    const int h0 = hh * 8 + blockIdx.z * 4;  // this wave: heads h0..h0+3
    const int lane = threadIdx.x;
    const int rowIdx = b * RR + r;

    const int nE = nEb[rowIdx];              // wave-uniform
    const float b2A = b2[h0], b2B = b2[h0 + 1], b2C = b2[h0 + 2], b2D = b2[h0 + 3];
    const float ebA = __expf(beta[h0]     - 10.f);
    const float ebB = __expf(beta[h0 + 1] - 10.f);
    const float ebC = __expf(beta[h0 + 2] - 10.f);
    const float ebD = __expf(beta[h0 + 3] - 10.f);

    const float* qA = Qb + (size_t)rowIdx * EE + h0 * DD;    // uniform -> SGPR
    const float* qB = qA + DD;
    const float* qC = qA + 2 * DD;
    const float* qD = qA + 3 * DD;
    const float* w10A = W1 + h0 * 32;
    const float* w11A = w10A + 16;
    const float* b1A  = b1 + h0 * 16;
    const float* w2A  = W2 + h0 * 16;

    // ---- scoring: lane e = edge e, 4 heads (independent chains) ----
    int c0 = 0, c1 = 0;
    float pA0 = 0.f, pB0 = 0.f, pC0 = 0.f, pD0 = 0.f;
    float pA1 = 0.f, pB1 = 0.f, pC1 = 0.f, pD1 = 0.f;
    if (lane < nE) {
        c0 = ecb[rowIdx * MAXE + lane];
        const float cw = ecwb[rowIdx * MAXE + lane];
        pA0 = score_edge(c0, cw, b, h0,     qA, Kb, w10A,      w11A,      b1A,      w2A,      b2A);
        pB0 = score_edge(c0, cw, b, h0 + 1, qB, Kb, w10A + 32, w11A + 32, b1A + 16, w2A + 16, b2B);
        pC0 = score_edge(c0, cw, b, h0 + 2, qC, Kb, w10A + 64, w11A + 64, b1A + 32, w2A + 32, b2C);
        pD0 = score_edge(c0, cw, b, h0 + 3, qD, Kb, w10A + 96, w11A + 96, b1A + 48, w2A + 48, b2D);
    }
    if (nE > 64) {                           // wave-uniform rare branch
        const int e1 = lane + 64;
        if (e1 < nE) {
            c1 = ecb[rowIdx * MAXE + e1];
            const float cw = ecwb[rowIdx * MAXE + e1];
            pA1 = score_edge(c1, cw, b, h0,     qA, Kb, w10A,      w11A,      b1A,      w2A,      b2A);
            pB1 = score_edge(c1, cw, b, h0 + 1, qB, Kb, w10A + 32, w11A + 32, b1A + 16, w2A + 16, b2B);
            pC1 = score_edge(c1, cw, b, h0 + 2, qC, Kb, w10A + 64, w11A + 64, b1A + 32, w2A + 32, b2C);
            pD1 = score_edge(c1, cw, b, h0 + 3, qD, Kb, w10A + 96, w11A + 96, b1A + 48, w2A + 48, b2D);
        }
    }

    // ---- Z: full-wave reduce, 4 heads ----
    float ZA = pA0 + pA1, ZB = pB0 + pB1, ZC = pC0 + pC1, ZD = pD0 + pD1;
#pragma unroll
    for (int off = 1; off < 64; off <<= 1) {
        ZA += __shfl_xor(ZA, off);
        ZB += __shfl_xor(ZB, off);
        ZC += __shfl_xor(ZC, off);
        ZD += __shfl_xor(ZD, off);
    }

    // ---- PV: 2 edges/iter, 4 heads -> 4 loads + 4 FMA chains in flight ----
    const int half = lane >> 5, d = lane & 31;
    const float wA0 = pA0 - ebA, wB0 = pB0 - ebB, wC0 = pC0 - ebC, wD0 = pD0 - ebD;
    float accA = 0.f, accB = 0.f, accC = 0.f, accD = 0.f;
    const int lim0 = (nE < 64) ? nE : 64;
    for (int eo = 0; eo < lim0; eo += 2) {
        const int e = eo + half;
        const float wa = __shfl(wA0, e & 63);
        const float wb = __shfl(wB0, e & 63);
        const float wc = __shfl(wC0, e & 63);
        const float wd = __shfl(wD0, e & 63);
        const int   ce = __shfl(c0, e & 63);   // c0=0 on invalid lanes: safe
        const bool ok = e < lim0;
        const size_t vb0 = ((size_t)b * CC + ce) * EE + h0 * DD + d;
        const float vA = Vb[vb0];
        const float vB = Vb[vb0 + DD];
        const float vC = Vb[vb0 + 2 * DD];
        const float vD = Vb[vb0 + 3 * DD];
        accA = fmaf(ok ? wa : 0.f, vA, accA);
        accB = fmaf(ok ? wb : 0.f, vB, accB);
        accC = fmaf(ok ? wc : 0.f, vC, accC);
        accD = fmaf(ok ? wd : 0.f, vD, accD);
    }
    if (nE > 64) {
        const float wA1 = pA1 - ebA, wB1 = pB1 - ebB, wC1 = pC1 - ebC, wD1 = pD1 - ebD;
        for (int eo = 64; eo < nE; eo += 2) {
            const int e = eo + half;
            const float wa = __shfl(wA1, (e - 64) & 63);
            const float wb = __shfl(wB1, (e - 64) & 63);
            const float wc = __shfl(wC1, (e - 64) & 63);
            const float wd = __shfl(wD1, (e - 64) & 63);
            const int   ce = __shfl(c1, (e - 64) & 63);
            const bool ok = e < nE;
            const size_t vb0 = ((size_t)b * CC + ce) * EE + h0 * DD + d;
            const float vA = Vb[vb0];
            const float vB = Vb[vb0 + DD];
            const float vC = Vb[vb0 + 2 * DD];
            const float vD = Vb[vb0 + 3 * DD];
            accA = fmaf(ok ? wa : 0.f, vA, accA);
            accB = fmaf(ok ? wb : 0.f, vB, accB);
            accC = fmaf(ok ? wc : 0.f, vC, accC);
            accD = fmaf(ok ? wd : 0.f, vD, accD);
        }
    }
    accA += __shfl_xor(accA, 32);
    accB += __shfl_xor(accB, 32);
    accC += __shfl_xor(accC, 32);
    accD += __shfl_xor(accD, 32);

    // ---- epilogue: background via Vsum, write packed hi/lo bf16 ----
    if (lane < 32) {
        const float bgZ = (float)(CC - nE);
        const float invA = 1.f / (ZA + bgZ * ebA);
        const float invB = 1.f / (ZB + bgZ * ebB);
        const float invC = 1.f / (ZC + bgZ * ebC);
        const float invD = 1.f / (ZD + bgZ * ebD);
        const float* vsp = Vsum + (b * HH + h0) * DD + d;
        const float oA = (accA + ebA * vsp[0])      * invA;
        const float oB = (accB + ebB * vsp[DD])     * invB;
        const float oC = (accC + ebC * vsp[2 * DD]) * invC;
        const float oD = (accD + ebD * vsp[3 * DD]) * invD;
        const int rm = rowIdx;
        const int base_in = (d >> 3) * 128 + (rm & 15) * 8 + (d & 7);
        ushort oh, ol;
        split1(oA, oh, ol);
        int dst = ((rm >> 4) * 16 + h0) * 512 + base_in;
        Hbh[dst] = oh; Hbl[dst] = ol;
        split1(oB, oh, ol);
        dst = ((rm >> 4) * 16 + h0 + 1) * 512 + base_in;
        Hbh[dst] = oh; Hbl[dst] = ol;
        split1(oC, oh, ol);
        dst = ((rm >> 4) * 16 + h0 + 2) * 512 + base_in;
        Hbh[dst] = oh; Hbl[dst] = ol;
        split1(oD, oh, ol);
        dst = ((rm >> 4) * 16 + h0 + 3) * 512 + base_in;
        Hbh[dst] = oh; Hbl[dst] = ol;
    }
}

// ---------------------------------------------------------------------------
extern "C" void kernel_launch(void* const* d_in, const int* in_sizes, int n_in,
                              void* d_out, int out_size, void* d_ws, size_t ws_size,
                              hipStream_t stream)
{
    const float* rowe = (const float*)d_in[0];
    const float* cole = (const float*)d_in[1];
    const float* cost = (const float*)d_in[2];
    const float* Wq   = (const float*)d_in[3];
    const float* bq   = (const float*)d_in[4];
    const float* Wk   = (const float*)d_in[5];
    const float* bk   = (const float*)d_in[6];
    const float* Wv   = (const float*)d_in[7];
    const float* bv   = (const float*)d_in[8];
    const float* Wo   = (const float*)d_in[9];
    const float* bo   = (const float*)d_in[10];
    const float* W1   = (const float*)d_in[11];
    const float* b1   = (const float*)d_in[12];
    const float* W2   = (const float*)d_in[13];
    const float* b2   = (const float*)d_in[14];
    const float* beta = (const float*)d_in[15];
    float* out = (float*)d_out;

    // ---- workspace carve ----
    char* cur = (char*)d_ws;
    float* Qb   = (float*)cur; cur += (size_t)MROWS * EE * 4;
    float* Kb   = (float*)cur; cur += (size_t)MROWS * EE * 4;
    float* Vb   = (float*)cur; cur += (size_t)MROWS * EE * 4;
    float* Vsum = (float*)cur; cur += (size_t)BB * HH * DD * 4;
    ushort* reh = (ushort*)cur; cur += (size_t)MROWS * EE * 2;
    ushort* rel = (ushort*)cur; cur += (size_t)MROWS * EE * 2;
    ushort* ceh = (ushort*)cur; cur += (size_t)MROWS * EE * 2;
    ushort* cel = (ushort*)cur; cur += (size_t)MROWS * EE * 2;
    ushort* wqh = (ushort*)cur; cur += (size_t)EE * EE * 2;
    ushort* wql = (ushort*)cur; cur += (size_t)EE * EE * 2;
    ushort* wkh = (ushort*)cur; cur += (size_t)EE * EE * 2;
    ushort* wkl = (ushort*)cur; cur += (size_t)EE * EE * 2;
    ushort* wvh = (ushort*)cur; cur += (size_t)EE * EE * 2;
    ushort* wvl = (ushort*)cur; cur += (size_t)EE * EE * 2;
    ushort* woh = (ushort*)cur; cur += (size_t)EE * EE * 2;
    ushort* wol = (ushort*)cur; cur += (size_t)EE * EE * 2;
    ushort* hbh = (ushort*)cur; cur += (size_t)MROWS * EE * 2;
    ushort* hbl = (ushort*)cur; cur += (size_t)MROWS * EE * 2;
    int*    ecb = (int*)cur;   cur += (size_t)MROWS * MAXE * 4;
    float* ecwb = (float*)cur; cur += (size_t)MROWS * MAXE * 4;
    int*    nEb = (int*)cur;   cur += (size_t)MROWS * 4;

    split_kernel<<<dim3(768, 6), 256, 0, stream>>>(
        rowe, cole, Wq, Wk, Wv, Wo,
        reh, rel, ceh, cel, wqh, wql, wkh, wkl, wvh, wvl, woh, wol);

    edges_kernel<<<dim3(RR, BB), 64, 0, stream>>>(cost, ecb, ecwb, nEb);

    dim3 g1(8, 24, 3);
    qkv_kernel<<<g1, 256, 0, stream>>>(reh, rel, ceh, cel,
                                       wqh, wql, wkh, wkl, wvh, wvl,
                                       bq, bk, bv, Qb, Kb, Vb);

    dim3 gv(16, 4);
    vsum_kernel<<<gv, 256, 0, stream>>>(Vb, Vsum);

    dim3 g2(8, RR, 2);   // x = (b,hh) -> XCD pin; y = row; z = head-quad
    attn_kernel<<<g2, 64, 0, stream>>>(Qb, Kb, Vb, ecb, ecwb, nEb,
                                       W1, b1, W2, b2, beta, Vsum, hbh, hbl);

    dim3 g3(8, 24, 1);
    oproj_kernel<<<g3, 256, 0, stream>>>(hbh, hbl, woh, wol, bo, out);
}